// Round 5
// baseline (520.975 us; speedup 1.0000x reference)
//
#include <hip/hip_runtime.h>
#include <math.h>

typedef unsigned int uint32;
typedef __attribute__((ext_vector_type(8))) short short8;
typedef __attribute__((ext_vector_type(4))) float f32x4;

#define BSH 7       // 128 nodes per bin
#define NBMAX 800   // >= ceil(N/128)
#define CHUNK 4096  // edges per chunk-block

// ---------------- helpers ----------------

__device__ __forceinline__ unsigned fkey(float f) {
  unsigned u = __float_as_uint(f);
  return (u & 0x80000000u) ? ~u : (u | 0x80000000u);
}
__device__ __forceinline__ float funkey(unsigned k) {
  unsigned u = (k & 0x80000000u) ? (k ^ 0x80000000u) : ~k;
  return __uint_as_float(u);
}
__device__ __forceinline__ unsigned short f2bf(float f) {  // RNE
  unsigned u = __float_as_uint(f);
  unsigned r = (u + 0x7FFFu + ((u >> 16) & 1u)) >> 16;
  return (unsigned short)r;
}
__device__ __forceinline__ float bf2f(unsigned short s) {
  return __uint_as_float(((unsigned)s) << 16);
}
// packed unsigned 16-bit max: 2 lanes/instr (VOP3P, gfx9+)
__device__ __forceinline__ uint32 pkmaxu(uint32 a, uint32 b) {
  uint32 d;
  asm("v_pk_max_u16 %0, %1, %2" : "=v"(d) : "v"(a), "v"(b));
  return d;
}
// sortable-key -> bf16 bits, both 16-bit halves of a dword
__device__ __forceinline__ uint32 unkey2(uint32 m) {
  uint32 t = (m >> 15) & 0x00010001u;          // 1 where key top bit set (orig >= 0)
  uint32 mask = (t * 0x7FFFu) ^ 0xFFFFFFFFu;   // ->0x8000 ; else ->0xFFFF
  return m ^ mask;
}
__device__ __forceinline__ f32x4 mfma16(short8 a, short8 b, f32x4 c) {
  return __builtin_amdgcn_mfma_f32_16x16x32_bf16(a, b, c, 0, 0, 0);
}

// ---------------- init ----------------

__global__ void init_kernel(unsigned* __restrict__ pooledU, unsigned* __restrict__ cmaxU,
                            float* __restrict__ denom, int* __restrict__ gcnt, int gh, int g) {
  int i = blockIdx.x * blockDim.x + threadIdx.x;
  if (i < gh) pooledU[i] = 0x80000000u;  // key(0.0f)
  if (i < g) { cmaxU[i] = 0u; denom[i] = 0.f; gcnt[i] = 0; }
}

// ---------------- fp32 -> sortable-key bf16 (layer-1 table) ----------------
// key(b) = (b & 0x8000) ? ~b : (b | 0x8000): u16 order == float order.

__global__ void cvt_key_kernel(const float* __restrict__ in, unsigned short* __restrict__ out,
                               int n4) {
  int i = blockIdx.x * blockDim.x + threadIdx.x;
  if (i < n4) {
    float4 v = ((const float4*)in)[i];
    ushort4 o;
    unsigned short b;
    b = f2bf(v.x); o.x = (b & 0x8000u) ? (unsigned short)~b : (unsigned short)(b | 0x8000u);
    b = f2bf(v.y); o.y = (b & 0x8000u) ? (unsigned short)~b : (unsigned short)(b | 0x8000u);
    b = f2bf(v.z); o.z = (b & 0x8000u) ? (unsigned short)~b : (unsigned short)(b | 0x8000u);
    b = f2bf(v.w); o.w = (b & 0x8000u) ? (unsigned short)~b : (unsigned short)(b | 0x8000u);
    ((ushort4*)out)[i] = o;
  }
}

// ---------------- pack weights into MFMA B-fragments (hi/lo bf16 split) -------
// B-frag layout for v_mfma_f32_16x16x32_bf16: lane l holds 8 k-consecutive
// elements: col = nt*16 + (l&15), k = ks*32 + (l>>4)*8 + e, e in [0,8).
// W stacked over K=2F: k<F -> Wl[k][col], else Wr[k-F][col].
// Groups g: L1 (F=128,KS=8): g=0..31 (nt=g>>3, ks=g&7);
//           L2 (F=64, KS=4): g=32..47; L3: g=48..63.
// out dwords: [set(hi=0,lo=1)][g][lane][p], p = e-pair. 128 KB total.

__global__ void pack_bfrag_kernel(const float* __restrict__ W1l, const float* __restrict__ W1r,
                                  const float* __restrict__ W2l, const float* __restrict__ W2r,
                                  const float* __restrict__ W3l, const float* __restrict__ W3r,
                                  uint32* __restrict__ out) {
  int i = blockIdx.x * blockDim.x + threadIdx.x;
  if (i >= 32768) return;
  int set = i >> 14;
  int r = i & 16383;
  int g = r >> 8;
  int lane = (r >> 2) & 63;
  int p = r & 3;
  const float *Wl, *Wr;
  int F, nt, ks;
  if (g < 32) {
    F = 128; Wl = W1l; Wr = W1r; nt = g >> 3; ks = g & 7;
  } else if (g < 48) {
    F = 64; Wl = W2l; Wr = W2r; int q = g - 32; nt = q >> 2; ks = q & 3;
  } else {
    F = 64; Wl = W3l; Wr = W3r; int q = g - 48; nt = q >> 2; ks = q & 3;
  }
  int col = nt * 16 + (lane & 15);
  int k0 = ks * 32 + ((lane >> 4) << 3) + 2 * p;
  float w0 = (k0 < F) ? Wl[k0 * 64 + col] : Wr[(k0 - F) * 64 + col];
  int k1 = k0 + 1;
  float w1 = (k1 < F) ? Wl[k1 * 64 + col] : Wr[(k1 - F) * 64 + col];
  if (set) {  // lo = residual after bf16(hi)
    w0 -= bf2f(f2bf(w0));
    w1 -= bf2f(f2bf(w1));
  }
  out[i] = ((uint32)f2bf(w1) << 16) | (uint32)f2bf(w0);
}

// ---------------- CSR build: zero-global-atomic counting sort ----------------
//  hist:   per-chunk per-bin counts (LDS atomics only), hist[b][c]
//  rowscan: exclusive scan of each bin row  -> per-(chunk,bin) offset; bsum[b]
//  binscan: exclusive scan of bin totals    -> bbase[b] (bbase[NB]=E)
//  bfill:  re-read edges, place packed recs at bbase[b]+hist[b][c]+i (LDS cursors)
//  place:  per-bin block: LDS node counters, scatter into 32KB L2-resident CSR
//          window. Node n's in-edges at csr[n*64 .. n*64+cnt[n]).

__global__ void hist_kernel(const int* __restrict__ dst, int* __restrict__ hist,
                            int E, int NB, int NC) {
  __shared__ int lcnt[NBMAX];
  int t = threadIdx.x, c = blockIdx.x;
  for (int i = t; i < NB; i += 256) lcnt[i] = 0;
  __syncthreads();
  int e0 = c * CHUNK, e1 = min(e0 + CHUNK, E);
  for (int e = e0 + t; e < e1; e += 256) atomicAdd(&lcnt[dst[e] >> BSH], 1);
  __syncthreads();
  for (int i = t; i < NB; i += 256) hist[(size_t)i * NC + c] = lcnt[i];
}

__global__ void rowscan_kernel(int* __restrict__ hist, int* __restrict__ bsum, int NB, int NC) {
  int wv = blockIdx.x * 4 + (threadIdx.x >> 6);
  int lane = threadIdx.x & 63;
  if (wv >= NB) return;
  int* row = hist + (size_t)wv * NC;
  int run = 0;
  for (int c = 0; c < NC; c += 64) {
    int idx = c + lane;
    int v = (idx < NC) ? row[idx] : 0;
    int incl = v;
#pragma unroll
    for (int off = 1; off < 64; off <<= 1) {
      int tt = __shfl_up(incl, off);
      if (lane >= off) incl += tt;
    }
    int tot = __shfl(incl, 63);
    if (idx < NC) row[idx] = run + incl - v;
    run += tot;
  }
  if (lane == 0) bsum[wv] = run;
}

__global__ void binscan_kernel(const int* __restrict__ bsum, int* __restrict__ bbase, int NB) {
  int lane = threadIdx.x;  // block = 64
  int run = 0;
  for (int c = 0; c < NB; c += 64) {
    int idx = c + lane;
    int v = (idx < NB) ? bsum[idx] : 0;
    int incl = v;
#pragma unroll
    for (int off = 1; off < 64; off <<= 1) {
      int tt = __shfl_up(incl, off);
      if (lane >= off) incl += tt;
    }
    if (idx < NB) bbase[idx] = run + incl - v;
    run += __shfl(incl, 63);
  }
  if (lane == 0) bbase[NB] = run;
}

__global__ void bfill_kernel(const int* __restrict__ src, const int* __restrict__ dst,
                             const int* __restrict__ hist, const int* __restrict__ bbase,
                             uint32* __restrict__ bbuf, int E, int NB, int NC) {
  __shared__ int lcur[NBMAX];
  int t = threadIdx.x, c = blockIdx.x;
  for (int i = t; i < NB; i += 256) lcur[i] = bbase[i] + hist[(size_t)i * NC + c];
  __syncthreads();
  int e0 = c * CHUNK, e1 = min(e0 + CHUNK, E);
  for (int e = e0 + t; e < e1; e += 256) {
    int d = dst[e], s = src[e];
    int b = d >> BSH;
    int pos = atomicAdd(&lcur[b], 1);
    bbuf[pos] = ((uint32)s << BSH) | (uint32)(d & ((1 << BSH) - 1));
  }
}

__global__ void place_kernel(const int* __restrict__ bbase, const uint32* __restrict__ bbuf,
                             int* __restrict__ cnt, int* __restrict__ csr, int N) {
  __shared__ int lcnt[1 << BSH];
  int b = blockIdx.x, t = threadIdx.x;
  for (int i = t; i < (1 << BSH); i += 256) lcnt[i] = 0;
  __syncthreads();
  int s0 = bbase[b], s1 = bbase[b + 1];
  for (int i = s0 + t; i < s1; i += 256) {
    uint32 rec = bbuf[i];
    int dl = rec & ((1 << BSH) - 1);
    int s = (int)(rec >> BSH);
    int pos = atomicAdd(&lcnt[dl], 1);
    if (pos < 64) csr[(((b << BSH) + dl) << 6) + pos] = s;
  }
  __syncthreads();
  int base = b << BSH;
  for (int i = t; i < (1 << BSH); i += 256) {
    int d = base + i;
    if (d < N) cnt[d] = min(lcnt[i], 64);
  }
}

// ---------------- fused SAGE layer ----------------
// Gather phase: packed-u16 max (v_pk_max_u16) on the raw table dwords -- no
// per-element unpack. L1 table is pre-transformed to sortable keys (mixed
// sign); L2/L3 tables are post-ReLU bf16 >= 0, where bit order == numeric
// order, so raw dword max is exact. 16-edge unroll = 8 row-loads in flight
// (latency-bound random gather). Dual-edge half-wave packing as before.
// Results (exact bf16, bit-identical to R4) staged to block-shared A matrix:
// A[32 nodes][K=2F] = [agg ; self]. Matmul phase: cooperative MFMA 16x16x32
// bf16, weights pre-packed as hi/lo bf16 B-fragments.

template <int F, bool OUT_F32>
__global__ void __launch_bounds__(256, 2) sage_layer(
    const unsigned short* __restrict__ xg,  // bf16/key table [nn,F]
    const int* __restrict__ cnt, const int* __restrict__ csr,
    const short8* __restrict__ BfHi, const short8* __restrict__ BfLo, int loff,
    const float* __restrict__ bl, float* __restrict__ outf,
    unsigned short* __restrict__ outb, int nn) {
  constexpr int NPW = 8;
  constexpr int PAD = F + 4;  // dwords per A row (K=2F bf16 = F dwords) + pad
  constexpr int KS = F / 16;  // k-steps of 32 over K=2F
  constexpr bool KEYED = (F == 128);  // layer-1 table is key-transformed
  const int lane = threadIdx.x & 63;
  const int wid = threadIdx.x >> 6;
  const int c = lane & 31;  // feature-chunk index within a row
  const int h = lane >> 5;  // half-wave: which of the 2 packed edges
  const int blk = blockIdx.x * 32;
  __shared__ uint32 Abuf[32][PAD];

  for (int j = 0; j < NPW; ++j) {
    int nl = wid * NPW + j;
    int n = blk + nl;
    if constexpr (F == 128) {
      uint32 m01 = 0u, m23 = 0u, sv = 0u;
      if (n < nn) {
        sv = *(const uint32*)(xg + ((size_t)n << 7) + 2 * lane);
        int dg = cnt[n];
        if (dg > 64) dg = 64;
        int k0 = n << 6, k1 = k0 + dg;
        if (k1 > k0) {
          int k = k0;
#define LD128(i) (*(const uint2*)(xg + ((size_t)(i) << 7) + 4 * c))
          for (; k + 16 <= k1; k += 16) {
            int i0 = csr[k + h], i1 = csr[k + 2 + h], i2 = csr[k + 4 + h], i3 = csr[k + 6 + h];
            int i4 = csr[k + 8 + h], i5 = csr[k + 10 + h], i6 = csr[k + 12 + h],
                i7 = csr[k + 14 + h];
            uint2 a0 = LD128(i0), a1 = LD128(i1), a2 = LD128(i2), a3 = LD128(i3);
            uint2 a4 = LD128(i4), a5 = LD128(i5), a6 = LD128(i6), a7 = LD128(i7);
            uint32 x0 = pkmaxu(pkmaxu(a0.x, a1.x), pkmaxu(a2.x, a3.x));
            uint32 x1 = pkmaxu(pkmaxu(a4.x, a5.x), pkmaxu(a6.x, a7.x));
            m01 = pkmaxu(m01, pkmaxu(x0, x1));
            uint32 y0 = pkmaxu(pkmaxu(a0.y, a1.y), pkmaxu(a2.y, a3.y));
            uint32 y1 = pkmaxu(pkmaxu(a4.y, a5.y), pkmaxu(a6.y, a7.y));
            m23 = pkmaxu(m23, pkmaxu(y0, y1));
          }
          for (; k + 2 <= k1; k += 2) {
            uint2 a = LD128(csr[k + h]);
            m01 = pkmaxu(m01, a.x);
            m23 = pkmaxu(m23, a.y);
          }
          if (k < k1) {  // single leftover edge: both halves load it (benign dup)
            uint2 a = LD128(csr[k]);
            m01 = pkmaxu(m01, a.x);
            m23 = pkmaxu(m23, a.y);
          }
#undef LD128
          m01 = pkmaxu(m01, (uint32)__shfl_xor((int)m01, 32));
          m23 = pkmaxu(m23, (uint32)__shfl_xor((int)m23, 32));
          if constexpr (KEYED) {
            m01 = unkey2(m01);
            m23 = unkey2(m23);
          }
        }
      }
      if (h == 0) {  // agg (exact bf16) at k=[0,F)
        uint2 mm;
        mm.x = m01;
        mm.y = m23;
        *(uint2*)&Abuf[nl][2 * c] = mm;
      }
      Abuf[nl][64 + lane] = KEYED ? unkey2(sv) : sv;  // self at k=[F,2F)
    } else {
      uint32 m01 = 0u, sv = 0u;
      if (n < nn) {
        if (h == 0) sv = *(const uint32*)(xg + ((size_t)n << 6) + 2 * c);
        int dg = cnt[n];
        if (dg > 64) dg = 64;
        int k0 = n << 6, k1 = k0 + dg;
        if (k1 > k0) {
          int k = k0;
#define LD64(i) (*(const uint32*)(xg + ((size_t)(i) << 6) + 2 * c))
          for (; k + 16 <= k1; k += 16) {
            int i0 = csr[k + h], i1 = csr[k + 2 + h], i2 = csr[k + 4 + h], i3 = csr[k + 6 + h];
            int i4 = csr[k + 8 + h], i5 = csr[k + 10 + h], i6 = csr[k + 12 + h],
                i7 = csr[k + 14 + h];
            uint32 a0 = LD64(i0), a1 = LD64(i1), a2 = LD64(i2), a3 = LD64(i3);
            uint32 a4 = LD64(i4), a5 = LD64(i5), a6 = LD64(i6), a7 = LD64(i7);
            uint32 x0 = pkmaxu(pkmaxu(a0, a1), pkmaxu(a2, a3));
            uint32 x1 = pkmaxu(pkmaxu(a4, a5), pkmaxu(a6, a7));
            m01 = pkmaxu(m01, pkmaxu(x0, x1));
          }
          for (; k + 2 <= k1; k += 2) m01 = pkmaxu(m01, LD64(csr[k + h]));
          if (k < k1) m01 = pkmaxu(m01, LD64(csr[k]));
#undef LD64
          m01 = pkmaxu(m01, (uint32)__shfl_xor((int)m01, 32));
        }
      }
      if (h == 0) {
        Abuf[nl][c] = m01;      // agg at k=[0,F)
        Abuf[nl][32 + c] = sv;  // self at k=[F,2F)
      }
    }
  }
  __syncthreads();  // A matrix is block-shared by the MFMA phase

  // ---- MFMA matmul: C[32][64] = A[32][2F] * Wstack[2F][64] + b ----
  const int l15 = lane & 15, lk = lane >> 4;
  const int mt = wid & 1;           // m-tile (rows mt*16..mt*16+15)
  const int ntb = (wid >> 1) << 1;  // this wave's 2 n-tiles: ntb, ntb+1
  const int arow = mt * 16 + l15;
  float bb0 = bl[ntb * 16 + l15], bb1 = bl[ntb * 16 + 16 + l15];
  f32x4 acc0 = {bb0, bb0, bb0, bb0};
  f32x4 acc1 = {bb1, bb1, bb1, bb1};
  const int gb0 = (loff + (ntb + 0) * KS) * 64 + lane;
  const int gb1 = (loff + (ntb + 1) * KS) * 64 + lane;
#pragma unroll 2
  for (int ks = 0; ks < KS; ++ks) {
    short8 a = *(const short8*)&Abuf[arow][ks * 16 + lk * 4];
    short8 bh0 = BfHi[gb0 + ks * 64];
    short8 bl0 = BfLo[gb0 + ks * 64];
    short8 bh1 = BfHi[gb1 + ks * 64];
    short8 bl1 = BfLo[gb1 + ks * 64];
    acc0 = mfma16(a, bh0, acc0);
    acc0 = mfma16(a, bl0, acc0);
    acc1 = mfma16(a, bh1, acc1);
    acc1 = mfma16(a, bl1, acc1);
  }
  // C layout: col = lane&15, row = (lane>>4)*4 + j
#pragma unroll
  for (int j = 0; j < 4; ++j) {
    int node = blk + mt * 16 + lk * 4 + j;
    if (node < nn) {
      float r0 = fmaxf(acc0[j], 0.f);
      float r1 = fmaxf(acc1[j], 0.f);
      if constexpr (OUT_F32) {
        outf[(size_t)node * 64 + ntb * 16 + l15] = r0;
        outf[(size_t)node * 64 + ntb * 16 + 16 + l15] = r1;
      } else {
        outb[(size_t)node * 64 + ntb * 16 + l15] = f2bf(r0);
        outb[(size_t)node * 64 + ntb * 16 + 16 + l15] = f2bf(r1);
      }
    }
  }
}

// ---------------- pooling tail ----------------

__global__ void cscore_kernel(const float* __restrict__ clo, const float* __restrict__ Wc,
                              const float* __restrict__ bc, const int* __restrict__ bat,
                              float* __restrict__ cbuf, unsigned* __restrict__ cmaxU,
                              int* __restrict__ gcnt, int n) {
  int i = blockIdx.x * blockDim.x + threadIdx.x;
  int lane = threadIdx.x & 63;
  float cv = -INFINITY;
  int g = -1;
  if (i < n) {
    const float4* row = (const float4*)(clo + (size_t)i * 16);
    float4 r0 = row[0], r1 = row[1], r2 = row[2], r3 = row[3];
    cv = bc[0];
    cv += r0.x * Wc[0] + r0.y * Wc[1] + r0.z * Wc[2] + r0.w * Wc[3];
    cv += r1.x * Wc[4] + r1.y * Wc[5] + r1.z * Wc[6] + r1.w * Wc[7];
    cv += r2.x * Wc[8] + r2.y * Wc[9] + r2.z * Wc[10] + r2.w * Wc[11];
    cv += r3.x * Wc[12] + r3.y * Wc[13] + r3.z * Wc[14] + r3.w * Wc[15];
    cbuf[i] = cv;
    g = bat[i];
  }
  int g0 = __shfl(g, 0), g63 = __shfl(g, 63);
  if (g0 >= 0 && g0 == g63) {  // whole wave in one graph (batch sorted)
    float m = cv;
#pragma unroll
    for (int off = 32; off; off >>= 1) m = fmaxf(m, __shfl_down(m, off));
    if (lane == 0) {
      atomicMax(&cmaxU[g0], fkey(m));
      atomicAdd(&gcnt[g0], 64);
    }
  } else if (g >= 0) {
    atomicMax(&cmaxU[g], fkey(cv));
    atomicAdd(&gcnt[g], 1);
  }
}

__global__ void esum_kernel(const float* __restrict__ cbuf, const int* __restrict__ bat,
                            const unsigned* __restrict__ cmaxU, float* __restrict__ ebuf,
                            float* __restrict__ denom, int n) {
  int i = blockIdx.x * blockDim.x + threadIdx.x;
  int lane = threadIdx.x & 63;
  float ev = 0.f;
  int g = -1;
  if (i < n) {
    g = bat[i];
    float cm = funkey(cmaxU[g]);
    ev = expf(cbuf[i] - cm);
    ebuf[i] = ev;
  }
  int g0 = __shfl(g, 0), g63 = __shfl(g, 63);
  if (g0 >= 0 && g0 == g63) {
    float s = ev;
#pragma unroll
    for (int off = 32; off; off >>= 1) s += __shfl_down(s, off);
    if (lane == 0) atomicAdd(&denom[g0], s);
  } else if (g >= 0) {
    atomicAdd(&denom[g], ev);
  }
}

__global__ void pool_kernel(const float* __restrict__ ebuf, const float* __restrict__ denom,
                            const int* __restrict__ gcnt, const int* __restrict__ bat,
                            const float* __restrict__ h3, unsigned* __restrict__ pooledU,
                            int n) {
  const int CH = 64;
  int wave = (blockIdx.x * blockDim.x + threadIdx.x) >> 6;
  int lane = threadIdx.x & 63;
  int nb = wave * CH;
  if (nb >= n) return;
  int ne = min(nb + CH, n);
  int curg = bat[nb];
  float factor = (float)gcnt[curg] / denom[curg];
  float lmax = -INFINITY;
  for (int nd = nb; nd < ne; ++nd) {
    int g = bat[nd];
    if (g != curg) {
      atomicMax(&pooledU[(size_t)curg * 64 + lane], fkey(lmax));
      curg = g;
      factor = (float)gcnt[g] / denom[g];
      lmax = -INFINITY;
    }
    float v = ebuf[nd] * factor * h3[(size_t)nd * 64 + lane];
    lmax = fmaxf(lmax, v);
  }
  atomicMax(&pooledU[(size_t)curg * 64 + lane], fkey(lmax));
}

__global__ void final_kernel(const unsigned* __restrict__ pooledU, const float* __restrict__ Wa1,
                             const float* __restrict__ ba1, const float* __restrict__ Wa2,
                             const float* __restrict__ ba2, float* __restrict__ out, int G) {
  int g = blockIdx.x;
  int lane = threadIdx.x;  // block = 64
  float v = funkey(pooledU[(size_t)g * 64 + lane]);
  if (!isfinite(v)) v = 0.f;
  float outv = 0.f;
#pragma unroll
  for (int j = 0; j < 16; ++j) {
    float psum = v * Wa1[lane * 16 + j];
#pragma unroll
    for (int off = 32; off; off >>= 1) psum += __shfl_down(psum, off);
    if (lane == 0) outv += fmaxf(psum + ba1[j], 0.f) * Wa2[j];
  }
  if (lane == 0) out[g] = outv + ba2[0];
}

// ---------------- launch ----------------

static inline size_t alignup(size_t x) { return (x + 255) & ~(size_t)255; }

extern "C" void kernel_launch(void* const* d_in, const int* in_sizes, int n_in,
                              void* d_out, int out_size, void* d_ws, size_t ws_size,
                              hipStream_t stream) {
  const float* x = (const float*)d_in[0];
  const int* ei = (const int*)d_in[1];
  const int* bat = (const int*)d_in[2];
  const float* clo = (const float*)d_in[3];
  const float* W1l = (const float*)d_in[4];
  const float* b1l = (const float*)d_in[5];
  const float* W1r = (const float*)d_in[6];
  const float* W2l = (const float*)d_in[7];
  const float* b2l = (const float*)d_in[8];
  const float* W2r = (const float*)d_in[9];
  const float* W3l = (const float*)d_in[10];
  const float* b3l = (const float*)d_in[11];
  const float* W3r = (const float*)d_in[12];
  const float* Wc = (const float*)d_in[13];
  const float* bc = (const float*)d_in[14];
  const float* Wa1 = (const float*)d_in[15];
  const float* ba1 = (const float*)d_in[16];
  const float* Wa2 = (const float*)d_in[17];
  const float* ba2 = (const float*)d_in[18];
  float* out = (float*)d_out;

  const int N = in_sizes[2];
  const int E = in_sizes[1] / 2;
  const int G = out_size;
  const int FIN = in_sizes[0] / N;  // 128

  char* p = (char*)d_ws;
  auto carve = [&](size_t bytes) {
    char* r = p;
    p += alignup(bytes);
    return r;
  };
  const int NB = (N + (1 << BSH) - 1) >> BSH;  // bins
  const int NC = (E + CHUNK - 1) / CHUNK;      // chunks
  int* cnt = (int*)carve((size_t)N * 4);
  int* csr = (int*)carve((size_t)N * 64 * 4);  // padded slots, 256 B per node
  unsigned short* xb = (unsigned short*)carve((size_t)N * FIN * 2);  // key table; h3 overlay
  unsigned short* hb1 = (unsigned short*)carve((size_t)N * 64 * 2);
  unsigned short* hb2 = (unsigned short*)carve((size_t)N * 64 * 2);
  float* cbuf = (float*)carve((size_t)N * 4);
  float* ebuf = (float*)carve((size_t)N * 4);
  unsigned* cmaxU = (unsigned*)carve((size_t)G * 4);
  float* denom = (float*)carve((size_t)G * 4);
  int* gcnt = (int*)carve((size_t)G * 4);
  unsigned* pooledU = (unsigned*)carve((size_t)G * 64 * 4);
  uint32* Bfrag = (uint32*)carve((size_t)32768 * 4);  // MFMA B-fragments hi+lo
  int* hist = (int*)carve((size_t)NB * NC * 4);
  int* bsum = (int*)carve((size_t)NB * 4);
  int* bbase = (int*)carve((size_t)(NB + 1) * 4);
  uint32* bbuf = (uint32*)carve((size_t)E * 4);  // exactly-compacted records
  float* h3 = (float*)xb;  // xb (N*128*2 B) dead after layer1; h3 = N*64*4 B fits exactly

  const short8* BfHi = (const short8*)Bfrag;
  const short8* BfLo = (const short8*)(Bfrag + 16384);

  const int* srcv = ei;
  const int* dstv = ei + E;

  int nb = (N + 255) / 256;
  hipLaunchKernelGGL(init_kernel, dim3((G * 64 + 255) / 256), dim3(256), 0, stream, pooledU,
                     cmaxU, denom, gcnt, G * 64, G);
  int ncvt = (N * FIN) / 4;
  hipLaunchKernelGGL(cvt_key_kernel, dim3((ncvt + 255) / 256), dim3(256), 0, stream, x, xb,
                     ncvt);
  hipLaunchKernelGGL(pack_bfrag_kernel, dim3(128), dim3(256), 0, stream, W1l, W1r, W2l, W2r,
                     W3l, W3r, Bfrag);
  hipLaunchKernelGGL(hist_kernel, dim3(NC), dim3(256), 0, stream, dstv, hist, E, NB, NC);
  hipLaunchKernelGGL(rowscan_kernel, dim3((NB + 3) / 4), dim3(256), 0, stream, hist, bsum, NB,
                     NC);
  hipLaunchKernelGGL(binscan_kernel, dim3(1), dim3(64), 0, stream, bsum, bbase, NB);
  hipLaunchKernelGGL(bfill_kernel, dim3(NC), dim3(256), 0, stream, srcv, dstv, hist, bbase,
                     bbuf, E, NB, NC);
  hipLaunchKernelGGL(place_kernel, dim3(NB), dim3(256), 0, stream, bbase, bbuf, cnt, csr, N);

  // 32 nodes per block (4 waves x NPW=8)
  int nblocks32 = (N + 31) / 32;
  hipLaunchKernelGGL((sage_layer<128, false>), dim3(nblocks32), dim3(256), 0, stream, xb, cnt,
                     csr, BfHi, BfLo, 0, b1l, (float*)nullptr, hb1, N);
  hipLaunchKernelGGL((sage_layer<64, false>), dim3(nblocks32), dim3(256), 0, stream, hb1, cnt,
                     csr, BfHi, BfLo, 32, b2l, (float*)nullptr, hb2, N);
  hipLaunchKernelGGL((sage_layer<64, true>), dim3(nblocks32), dim3(256), 0, stream, hb2, cnt,
                     csr, BfHi, BfLo, 48, b3l, h3, (unsigned short*)nullptr, N);

  hipLaunchKernelGGL(cscore_kernel, dim3(nb), dim3(256), 0, stream, clo, Wc, bc, bat, cbuf,
                     cmaxU, gcnt, N);
  hipLaunchKernelGGL(esum_kernel, dim3(nb), dim3(256), 0, stream, cbuf, bat, cmaxU, ebuf, denom,
                     N);
  int pw = (N + 63) / 64;
  int pb = (pw + 3) / 4;
  hipLaunchKernelGGL(pool_kernel, dim3(pb), dim3(256), 0, stream, ebuf, denom, gcnt, bat, h3,
                     pooledU, N);
  hipLaunchKernelGGL(final_kernel, dim3(G), dim3(64), 0, stream, pooledU, Wa1, ba1, Wa2, ba2,
                     out, G);
}

// Round 6
// 444.160 us; speedup vs baseline: 1.1729x; 1.1729x over previous
//
#include <hip/hip_runtime.h>
#include <math.h>

typedef unsigned int uint32;
typedef __attribute__((ext_vector_type(8))) short short8;
typedef __attribute__((ext_vector_type(4))) float f32x4;

#define BSH 7       // 128 nodes per bin
#define NBMAX 800   // >= ceil(N/128)
#define CHUNK 4096  // edges per chunk-block

// ---------------- helpers ----------------

__device__ __forceinline__ unsigned fkey(float f) {
  unsigned u = __float_as_uint(f);
  return (u & 0x80000000u) ? ~u : (u | 0x80000000u);
}
__device__ __forceinline__ float funkey(unsigned k) {
  unsigned u = (k & 0x80000000u) ? (k ^ 0x80000000u) : ~k;
  return __uint_as_float(u);
}
__device__ __forceinline__ unsigned short f2bf(float f) {  // RNE
  unsigned u = __float_as_uint(f);
  unsigned r = (u + 0x7FFFu + ((u >> 16) & 1u)) >> 16;
  return (unsigned short)r;
}
__device__ __forceinline__ float bf2f(unsigned short s) {
  return __uint_as_float(((unsigned)s) << 16);
}
// packed unsigned 16-bit max: 2 lanes/instr (VOP3P, gfx9+)
__device__ __forceinline__ uint32 pkmaxu(uint32 a, uint32 b) {
  uint32 d;
  asm("v_pk_max_u16 %0, %1, %2" : "=v"(d) : "v"(a), "v"(b));
  return d;
}
// sortable-key -> bf16 bits, both 16-bit halves of a dword
__device__ __forceinline__ uint32 unkey2(uint32 m) {
  uint32 t = (m >> 15) & 0x00010001u;          // 1 where key top bit set (orig >= 0)
  uint32 mask = (t * 0x7FFFu) ^ 0xFFFFFFFFu;   // ->0x8000 ; else ->0xFFFF
  return m ^ mask;
}
__device__ __forceinline__ f32x4 mfma16(short8 a, short8 b, f32x4 c) {
  return __builtin_amdgcn_mfma_f32_16x16x32_bf16(a, b, c, 0, 0, 0);
}

// ---------------- init ----------------

__global__ void init_kernel(unsigned* __restrict__ pooledU, unsigned* __restrict__ cmaxU,
                            float* __restrict__ denom, int* __restrict__ gcnt, int gh, int g) {
  int i = blockIdx.x * blockDim.x + threadIdx.x;
  if (i < gh) pooledU[i] = 0x80000000u;  // key(0.0f)
  if (i < g) { cmaxU[i] = 0u; denom[i] = 0.f; gcnt[i] = 0; }
}

// ---------------- fp32 -> sortable-key bf16 (layer-1 table) ----------------
// key(b) = (b & 0x8000) ? ~b : (b | 0x8000): u16 order == float order.

__global__ void cvt_key_kernel(const float* __restrict__ in, unsigned short* __restrict__ out,
                               int n4) {
  int i = blockIdx.x * blockDim.x + threadIdx.x;
  if (i < n4) {
    float4 v = ((const float4*)in)[i];
    ushort4 o;
    unsigned short b;
    b = f2bf(v.x); o.x = (b & 0x8000u) ? (unsigned short)~b : (unsigned short)(b | 0x8000u);
    b = f2bf(v.y); o.y = (b & 0x8000u) ? (unsigned short)~b : (unsigned short)(b | 0x8000u);
    b = f2bf(v.z); o.z = (b & 0x8000u) ? (unsigned short)~b : (unsigned short)(b | 0x8000u);
    b = f2bf(v.w); o.w = (b & 0x8000u) ? (unsigned short)~b : (unsigned short)(b | 0x8000u);
    ((ushort4*)out)[i] = o;
  }
}

// ---------------- pack weights into MFMA B-fragments (hi/lo bf16 split) -------
// B-frag layout for v_mfma_f32_16x16x32_bf16: lane l holds 8 k-consecutive
// elements: col = nt*16 + (l&15), k = ks*32 + (l>>4)*8 + e, e in [0,8).
// W stacked over K=2F: k<F -> Wl[k][col], else Wr[k-F][col].
// Groups g: L1 (F=128,KS=8): g=0..31 (nt=g>>3, ks=g&7);
//           L2 (F=64, KS=4): g=32..47; L3: g=48..63.
// out dwords: [set(hi=0,lo=1)][g][lane][p], p = e-pair. 128 KB total.

__global__ void pack_bfrag_kernel(const float* __restrict__ W1l, const float* __restrict__ W1r,
                                  const float* __restrict__ W2l, const float* __restrict__ W2r,
                                  const float* __restrict__ W3l, const float* __restrict__ W3r,
                                  uint32* __restrict__ out) {
  int i = blockIdx.x * blockDim.x + threadIdx.x;
  if (i >= 32768) return;
  int set = i >> 14;
  int r = i & 16383;
  int g = r >> 8;
  int lane = (r >> 2) & 63;
  int p = r & 3;
  const float *Wl, *Wr;
  int F, nt, ks;
  if (g < 32) {
    F = 128; Wl = W1l; Wr = W1r; nt = g >> 3; ks = g & 7;
  } else if (g < 48) {
    F = 64; Wl = W2l; Wr = W2r; int q = g - 32; nt = q >> 2; ks = q & 3;
  } else {
    F = 64; Wl = W3l; Wr = W3r; int q = g - 48; nt = q >> 2; ks = q & 3;
  }
  int col = nt * 16 + (lane & 15);
  int k0 = ks * 32 + ((lane >> 4) << 3) + 2 * p;
  float w0 = (k0 < F) ? Wl[k0 * 64 + col] : Wr[(k0 - F) * 64 + col];
  int k1 = k0 + 1;
  float w1 = (k1 < F) ? Wl[k1 * 64 + col] : Wr[(k1 - F) * 64 + col];
  if (set) {  // lo = residual after bf16(hi)
    w0 -= bf2f(f2bf(w0));
    w1 -= bf2f(f2bf(w1));
  }
  out[i] = ((uint32)f2bf(w1) << 16) | (uint32)f2bf(w0);
}

// ---------------- CSR build: zero-global-atomic counting sort ----------------
//  hist:   per-chunk per-bin counts (LDS atomics only), hist[b][c]
//  rowscan: exclusive scan of each bin row  -> per-(chunk,bin) offset; bsum[b]
//  binscan: exclusive scan of bin totals    -> bbase[b] (bbase[NB]=E)
//  bfill:  re-read edges, place packed recs at bbase[b]+hist[b][c]+i (LDS cursors)
//  place:  per-bin block: LDS node counters, scatter into 32KB L2-resident CSR
//          window. Node n's in-edges at csr[n*64 .. n*64+cnt[n]).

__global__ void hist_kernel(const int* __restrict__ dst, int* __restrict__ hist,
                            int E, int NB, int NC) {
  __shared__ int lcnt[NBMAX];
  int t = threadIdx.x, c = blockIdx.x;
  for (int i = t; i < NB; i += 256) lcnt[i] = 0;
  __syncthreads();
  int e0 = c * CHUNK, e1 = min(e0 + CHUNK, E);
  for (int e = e0 + t; e < e1; e += 256) atomicAdd(&lcnt[dst[e] >> BSH], 1);
  __syncthreads();
  for (int i = t; i < NB; i += 256) hist[(size_t)i * NC + c] = lcnt[i];
}

__global__ void rowscan_kernel(int* __restrict__ hist, int* __restrict__ bsum, int NB, int NC) {
  int wv = blockIdx.x * 4 + (threadIdx.x >> 6);
  int lane = threadIdx.x & 63;
  if (wv >= NB) return;
  int* row = hist + (size_t)wv * NC;
  int run = 0;
  for (int c = 0; c < NC; c += 64) {
    int idx = c + lane;
    int v = (idx < NC) ? row[idx] : 0;
    int incl = v;
#pragma unroll
    for (int off = 1; off < 64; off <<= 1) {
      int tt = __shfl_up(incl, off);
      if (lane >= off) incl += tt;
    }
    int tot = __shfl(incl, 63);
    if (idx < NC) row[idx] = run + incl - v;
    run += tot;
  }
  if (lane == 0) bsum[wv] = run;
}

__global__ void binscan_kernel(const int* __restrict__ bsum, int* __restrict__ bbase, int NB) {
  int lane = threadIdx.x;  // block = 64
  int run = 0;
  for (int c = 0; c < NB; c += 64) {
    int idx = c + lane;
    int v = (idx < NB) ? bsum[idx] : 0;
    int incl = v;
#pragma unroll
    for (int off = 1; off < 64; off <<= 1) {
      int tt = __shfl_up(incl, off);
      if (lane >= off) incl += tt;
    }
    if (idx < NB) bbase[idx] = run + incl - v;
    run += __shfl(incl, 63);
  }
  if (lane == 0) bbase[NB] = run;
}

__global__ void bfill_kernel(const int* __restrict__ src, const int* __restrict__ dst,
                             const int* __restrict__ hist, const int* __restrict__ bbase,
                             uint32* __restrict__ bbuf, int E, int NB, int NC) {
  __shared__ int lcur[NBMAX];
  int t = threadIdx.x, c = blockIdx.x;
  for (int i = t; i < NB; i += 256) lcur[i] = bbase[i] + hist[(size_t)i * NC + c];
  __syncthreads();
  int e0 = c * CHUNK, e1 = min(e0 + CHUNK, E);
  for (int e = e0 + t; e < e1; e += 256) {
    int d = dst[e], s = src[e];
    int b = d >> BSH;
    int pos = atomicAdd(&lcur[b], 1);
    bbuf[pos] = ((uint32)s << BSH) | (uint32)(d & ((1 << BSH) - 1));
  }
}

__global__ void place_kernel(const int* __restrict__ bbase, const uint32* __restrict__ bbuf,
                             int* __restrict__ cnt, int* __restrict__ csr, int N) {
  __shared__ int lcnt[1 << BSH];
  int b = blockIdx.x, t = threadIdx.x;
  for (int i = t; i < (1 << BSH); i += 256) lcnt[i] = 0;
  __syncthreads();
  int s0 = bbase[b], s1 = bbase[b + 1];
  for (int i = s0 + t; i < s1; i += 256) {
    uint32 rec = bbuf[i];
    int dl = rec & ((1 << BSH) - 1);
    int s = (int)(rec >> BSH);
    int pos = atomicAdd(&lcnt[dl], 1);
    if (pos < 64) csr[(((b << BSH) + dl) << 6) + pos] = s;
  }
  __syncthreads();
  int base = b << BSH;
  for (int i = t; i < (1 << BSH); i += 256) {
    int d = base + i;
    if (d < N) cnt[d] = min(lcnt[i], 64);
  }
}

// ---------------- fused SAGE layer ----------------
// Gather phase: packed-u16 max (v_pk_max_u16) on raw table dwords (no unpack;
// L1 table key-transformed for mixed sign, L2/L3 post-ReLU >= 0 so raw u16
// order == float order). CLAMPED-INDEX FULL UNROLL: every neighborhood is
// rounded up to a multiple of 16 edges by clamping the slot index to the last
// real edge (max is idempotent; dup slots reread the same L1-hot row). This
// keeps 8 row-loads in flight for EVERY node -- R5's tail loop collapsed MLP
// to 1 load for the ~47% of nodes with deg<16. Results bit-identical.
// Matmul phase: cooperative MFMA 16x16x32 bf16 on block-shared A (unchanged).

template <int F, bool OUT_F32>
__global__ void __launch_bounds__(256, 2) sage_layer(
    const unsigned short* __restrict__ xg,  // bf16/key table [nn,F]
    const int* __restrict__ cnt, const int* __restrict__ csr,
    const short8* __restrict__ BfHi, const short8* __restrict__ BfLo, int loff,
    const float* __restrict__ bl, float* __restrict__ outf,
    unsigned short* __restrict__ outb, int nn) {
  constexpr int NPW = 8;
  constexpr int PAD = F + 4;  // dwords per A row (K=2F bf16 = F dwords) + pad
  constexpr int KS = F / 16;  // k-steps of 32 over K=2F
  constexpr bool KEYED = (F == 128);  // layer-1 table is key-transformed
  const int lane = threadIdx.x & 63;
  const int wid = threadIdx.x >> 6;
  const int c = lane & 31;  // feature-chunk index within a row
  const int h = lane >> 5;  // half-wave: which of the 2 packed edges
  const int blk = blockIdx.x * 32;
  __shared__ uint32 Abuf[32][PAD];

  for (int j = 0; j < NPW; ++j) {
    int nl = wid * NPW + j;
    int n = blk + nl;
    if constexpr (F == 128) {
      uint32 m01 = 0u, m23 = 0u, sv = 0u;
      if (n < nn) {
        sv = *(const uint32*)(xg + ((size_t)n << 7) + 2 * lane);
        int dg = cnt[n];
        if (dg > 64) dg = 64;
        int k0 = n << 6, k1 = k0 + dg;
        if (k1 > k0) {
          int km = k1 - 1;
#define LD128(i) (*(const uint2*)(xg + ((size_t)(i) << 7) + 4 * c))
          for (int k = k0; k < k1; k += 16) {
            int i0 = csr[min(k + 0 + h, km)], i1 = csr[min(k + 2 + h, km)];
            int i2 = csr[min(k + 4 + h, km)], i3 = csr[min(k + 6 + h, km)];
            int i4 = csr[min(k + 8 + h, km)], i5 = csr[min(k + 10 + h, km)];
            int i6 = csr[min(k + 12 + h, km)], i7 = csr[min(k + 14 + h, km)];
            uint2 a0 = LD128(i0), a1 = LD128(i1), a2 = LD128(i2), a3 = LD128(i3);
            uint2 a4 = LD128(i4), a5 = LD128(i5), a6 = LD128(i6), a7 = LD128(i7);
            uint32 x0 = pkmaxu(pkmaxu(a0.x, a1.x), pkmaxu(a2.x, a3.x));
            uint32 x1 = pkmaxu(pkmaxu(a4.x, a5.x), pkmaxu(a6.x, a7.x));
            m01 = pkmaxu(m01, pkmaxu(x0, x1));
            uint32 y0 = pkmaxu(pkmaxu(a0.y, a1.y), pkmaxu(a2.y, a3.y));
            uint32 y1 = pkmaxu(pkmaxu(a4.y, a5.y), pkmaxu(a6.y, a7.y));
            m23 = pkmaxu(m23, pkmaxu(y0, y1));
          }
#undef LD128
          m01 = pkmaxu(m01, (uint32)__shfl_xor((int)m01, 32));
          m23 = pkmaxu(m23, (uint32)__shfl_xor((int)m23, 32));
          if constexpr (KEYED) {
            m01 = unkey2(m01);
            m23 = unkey2(m23);
          }
        }
      }
      if (h == 0) {  // agg (exact bf16) at k=[0,F)
        uint2 mm;
        mm.x = m01;
        mm.y = m23;
        *(uint2*)&Abuf[nl][2 * c] = mm;
      }
      Abuf[nl][64 + lane] = KEYED ? unkey2(sv) : sv;  // self at k=[F,2F)
    } else {
      uint32 m01 = 0u, sv = 0u;
      if (n < nn) {
        if (h == 0) sv = *(const uint32*)(xg + ((size_t)n << 6) + 2 * c);
        int dg = cnt[n];
        if (dg > 64) dg = 64;
        int k0 = n << 6, k1 = k0 + dg;
        if (k1 > k0) {
          int km = k1 - 1;
#define LD64(i) (*(const uint32*)(xg + ((size_t)(i) << 6) + 2 * c))
          for (int k = k0; k < k1; k += 16) {
            int i0 = csr[min(k + 0 + h, km)], i1 = csr[min(k + 2 + h, km)];
            int i2 = csr[min(k + 4 + h, km)], i3 = csr[min(k + 6 + h, km)];
            int i4 = csr[min(k + 8 + h, km)], i5 = csr[min(k + 10 + h, km)];
            int i6 = csr[min(k + 12 + h, km)], i7 = csr[min(k + 14 + h, km)];
            uint32 a0 = LD64(i0), a1 = LD64(i1), a2 = LD64(i2), a3 = LD64(i3);
            uint32 a4 = LD64(i4), a5 = LD64(i5), a6 = LD64(i6), a7 = LD64(i7);
            uint32 x0 = pkmaxu(pkmaxu(a0, a1), pkmaxu(a2, a3));
            uint32 x1 = pkmaxu(pkmaxu(a4, a5), pkmaxu(a6, a7));
            m01 = pkmaxu(m01, pkmaxu(x0, x1));
          }
#undef LD64
          m01 = pkmaxu(m01, (uint32)__shfl_xor((int)m01, 32));
        }
      }
      if (h == 0) {
        Abuf[nl][c] = m01;      // agg at k=[0,F)
        Abuf[nl][32 + c] = sv;  // self at k=[F,2F)
      }
    }
  }
  __syncthreads();  // A matrix is block-shared by the MFMA phase

  // ---- MFMA matmul: C[32][64] = A[32][2F] * Wstack[2F][64] + b ----
  const int l15 = lane & 15, lk = lane >> 4;
  const int mt = wid & 1;           // m-tile (rows mt*16..mt*16+15)
  const int ntb = (wid >> 1) << 1;  // this wave's 2 n-tiles: ntb, ntb+1
  const int arow = mt * 16 + l15;
  float bb0 = bl[ntb * 16 + l15], bb1 = bl[ntb * 16 + 16 + l15];
  f32x4 acc0 = {bb0, bb0, bb0, bb0};
  f32x4 acc1 = {bb1, bb1, bb1, bb1};
  const int gb0 = (loff + (ntb + 0) * KS) * 64 + lane;
  const int gb1 = (loff + (ntb + 1) * KS) * 64 + lane;
#pragma unroll 2
  for (int ks = 0; ks < KS; ++ks) {
    short8 a = *(const short8*)&Abuf[arow][ks * 16 + lk * 4];
    short8 bh0 = BfHi[gb0 + ks * 64];
    short8 bl0 = BfLo[gb0 + ks * 64];
    short8 bh1 = BfHi[gb1 + ks * 64];
    short8 bl1 = BfLo[gb1 + ks * 64];
    acc0 = mfma16(a, bh0, acc0);
    acc0 = mfma16(a, bl0, acc0);
    acc1 = mfma16(a, bh1, acc1);
    acc1 = mfma16(a, bl1, acc1);
  }
  // C layout: col = lane&15, row = (lane>>4)*4 + j
#pragma unroll
  for (int j = 0; j < 4; ++j) {
    int node = blk + mt * 16 + lk * 4 + j;
    if (node < nn) {
      float r0 = fmaxf(acc0[j], 0.f);
      float r1 = fmaxf(acc1[j], 0.f);
      if constexpr (OUT_F32) {
        outf[(size_t)node * 64 + ntb * 16 + l15] = r0;
        outf[(size_t)node * 64 + ntb * 16 + 16 + l15] = r1;
      } else {
        outb[(size_t)node * 64 + ntb * 16 + l15] = f2bf(r0);
        outb[(size_t)node * 64 + ntb * 16 + 16 + l15] = f2bf(r1);
      }
    }
  }
}

// ---------------- pooling tail ----------------

__global__ void cscore_kernel(const float* __restrict__ clo, const float* __restrict__ Wc,
                              const float* __restrict__ bc, const int* __restrict__ bat,
                              float* __restrict__ cbuf, unsigned* __restrict__ cmaxU,
                              int* __restrict__ gcnt, int n) {
  int i = blockIdx.x * blockDim.x + threadIdx.x;
  int lane = threadIdx.x & 63;
  float cv = -INFINITY;
  int g = -1;
  if (i < n) {
    const float4* row = (const float4*)(clo + (size_t)i * 16);
    float4 r0 = row[0], r1 = row[1], r2 = row[2], r3 = row[3];
    cv = bc[0];
    cv += r0.x * Wc[0] + r0.y * Wc[1] + r0.z * Wc[2] + r0.w * Wc[3];
    cv += r1.x * Wc[4] + r1.y * Wc[5] + r1.z * Wc[6] + r1.w * Wc[7];
    cv += r2.x * Wc[8] + r2.y * Wc[9] + r2.z * Wc[10] + r2.w * Wc[11];
    cv += r3.x * Wc[12] + r3.y * Wc[13] + r3.z * Wc[14] + r3.w * Wc[15];
    cbuf[i] = cv;
    g = bat[i];
  }
  int g0 = __shfl(g, 0), g63 = __shfl(g, 63);
  if (g0 >= 0 && g0 == g63) {  // whole wave in one graph (batch sorted)
    float m = cv;
#pragma unroll
    for (int off = 32; off; off >>= 1) m = fmaxf(m, __shfl_down(m, off));
    if (lane == 0) {
      atomicMax(&cmaxU[g0], fkey(m));
      atomicAdd(&gcnt[g0], 64);
    }
  } else if (g >= 0) {
    atomicMax(&cmaxU[g], fkey(cv));
    atomicAdd(&gcnt[g], 1);
  }
}

__global__ void esum_kernel(const float* __restrict__ cbuf, const int* __restrict__ bat,
                            const unsigned* __restrict__ cmaxU, float* __restrict__ ebuf,
                            float* __restrict__ denom, int n) {
  int i = blockIdx.x * blockDim.x + threadIdx.x;
  int lane = threadIdx.x & 63;
  float ev = 0.f;
  int g = -1;
  if (i < n) {
    g = bat[i];
    float cm = funkey(cmaxU[g]);
    ev = expf(cbuf[i] - cm);
    ebuf[i] = ev;
  }
  int g0 = __shfl(g, 0), g63 = __shfl(g, 63);
  if (g0 >= 0 && g0 == g63) {
    float s = ev;
#pragma unroll
    for (int off = 32; off; off >>= 1) s += __shfl_down(s, off);
    if (lane == 0) atomicAdd(&denom[g0], s);
  } else if (g >= 0) {
    atomicAdd(&denom[g], ev);
  }
}

__global__ void pool_kernel(const float* __restrict__ ebuf, const float* __restrict__ denom,
                            const int* __restrict__ gcnt, const int* __restrict__ bat,
                            const float* __restrict__ h3, unsigned* __restrict__ pooledU,
                            int n) {
  const int CH = 64;
  int wave = (blockIdx.x * blockDim.x + threadIdx.x) >> 6;
  int lane = threadIdx.x & 63;
  int nb = wave * CH;
  if (nb >= n) return;
  int ne = min(nb + CH, n);
  int curg = bat[nb];
  float factor = (float)gcnt[curg] / denom[curg];
  float lmax = -INFINITY;
  for (int nd = nb; nd < ne; ++nd) {
    int g = bat[nd];
    if (g != curg) {
      atomicMax(&pooledU[(size_t)curg * 64 + lane], fkey(lmax));
      curg = g;
      factor = (float)gcnt[g] / denom[g];
      lmax = -INFINITY;
    }
    float v = ebuf[nd] * factor * h3[(size_t)nd * 64 + lane];
    lmax = fmaxf(lmax, v);
  }
  atomicMax(&pooledU[(size_t)curg * 64 + lane], fkey(lmax));
}

__global__ void final_kernel(const unsigned* __restrict__ pooledU, const float* __restrict__ Wa1,
                             const float* __restrict__ ba1, const float* __restrict__ Wa2,
                             const float* __restrict__ ba2, float* __restrict__ out, int G) {
  int g = blockIdx.x;
  int lane = threadIdx.x;  // block = 64
  float v = funkey(pooledU[(size_t)g * 64 + lane]);
  if (!isfinite(v)) v = 0.f;
  float outv = 0.f;
#pragma unroll
  for (int j = 0; j < 16; ++j) {
    float psum = v * Wa1[lane * 16 + j];
#pragma unroll
    for (int off = 32; off; off >>= 1) psum += __shfl_down(psum, off);
    if (lane == 0) outv += fmaxf(psum + ba1[j], 0.f) * Wa2[j];
  }
  if (lane == 0) out[g] = outv + ba2[0];
}

// ---------------- launch ----------------

static inline size_t alignup(size_t x) { return (x + 255) & ~(size_t)255; }

extern "C" void kernel_launch(void* const* d_in, const int* in_sizes, int n_in,
                              void* d_out, int out_size, void* d_ws, size_t ws_size,
                              hipStream_t stream) {
  const float* x = (const float*)d_in[0];
  const int* ei = (const int*)d_in[1];
  const int* bat = (const int*)d_in[2];
  const float* clo = (const float*)d_in[3];
  const float* W1l = (const float*)d_in[4];
  const float* b1l = (const float*)d_in[5];
  const float* W1r = (const float*)d_in[6];
  const float* W2l = (const float*)d_in[7];
  const float* b2l = (const float*)d_in[8];
  const float* W2r = (const float*)d_in[9];
  const float* W3l = (const float*)d_in[10];
  const float* b3l = (const float*)d_in[11];
  const float* W3r = (const float*)d_in[12];
  const float* Wc = (const float*)d_in[13];
  const float* bc = (const float*)d_in[14];
  const float* Wa1 = (const float*)d_in[15];
  const float* ba1 = (const float*)d_in[16];
  const float* Wa2 = (const float*)d_in[17];
  const float* ba2 = (const float*)d_in[18];
  float* out = (float*)d_out;

  const int N = in_sizes[2];
  const int E = in_sizes[1] / 2;
  const int G = out_size;
  const int FIN = in_sizes[0] / N;  // 128

  char* p = (char*)d_ws;
  auto carve = [&](size_t bytes) {
    char* r = p;
    p += alignup(bytes);
    return r;
  };
  const int NB = (N + (1 << BSH) - 1) >> BSH;  // bins
  const int NC = (E + CHUNK - 1) / CHUNK;      // chunks
  int* cnt = (int*)carve((size_t)N * 4);
  int* csr = (int*)carve((size_t)N * 64 * 4);  // padded slots, 256 B per node
  unsigned short* xb = (unsigned short*)carve((size_t)N * FIN * 2);  // key table; h3 overlay
  unsigned short* hb1 = (unsigned short*)carve((size_t)N * 64 * 2);
  unsigned short* hb2 = (unsigned short*)carve((size_t)N * 64 * 2);
  float* cbuf = (float*)carve((size_t)N * 4);
  float* ebuf = (float*)carve((size_t)N * 4);
  unsigned* cmaxU = (unsigned*)carve((size_t)G * 4);
  float* denom = (float*)carve((size_t)G * 4);
  int* gcnt = (int*)carve((size_t)G * 4);
  unsigned* pooledU = (unsigned*)carve((size_t)G * 64 * 4);
  uint32* Bfrag = (uint32*)carve((size_t)32768 * 4);  // MFMA B-fragments hi+lo
  int* hist = (int*)carve((size_t)NB * NC * 4);
  int* bsum = (int*)carve((size_t)NB * 4);
  int* bbase = (int*)carve((size_t)(NB + 1) * 4);
  uint32* bbuf = (uint32*)carve((size_t)E * 4);  // exactly-compacted records
  float* h3 = (float*)xb;  // xb (N*128*2 B) dead after layer1; h3 = N*64*4 B fits exactly

  const short8* BfHi = (const short8*)Bfrag;
  const short8* BfLo = (const short8*)(Bfrag + 16384);

  const int* srcv = ei;
  const int* dstv = ei + E;

  int nb = (N + 255) / 256;
  hipLaunchKernelGGL(init_kernel, dim3((G * 64 + 255) / 256), dim3(256), 0, stream, pooledU,
                     cmaxU, denom, gcnt, G * 64, G);
  int ncvt = (N * FIN) / 4;
  hipLaunchKernelGGL(cvt_key_kernel, dim3((ncvt + 255) / 256), dim3(256), 0, stream, x, xb,
                     ncvt);
  hipLaunchKernelGGL(pack_bfrag_kernel, dim3(128), dim3(256), 0, stream, W1l, W1r, W2l, W2r,
                     W3l, W3r, Bfrag);
  hipLaunchKernelGGL(hist_kernel, dim3(NC), dim3(256), 0, stream, dstv, hist, E, NB, NC);
  hipLaunchKernelGGL(rowscan_kernel, dim3((NB + 3) / 4), dim3(256), 0, stream, hist, bsum, NB,
                     NC);
  hipLaunchKernelGGL(binscan_kernel, dim3(1), dim3(64), 0, stream, bsum, bbase, NB);
  hipLaunchKernelGGL(bfill_kernel, dim3(NC), dim3(256), 0, stream, srcv, dstv, hist, bbase,
                     bbuf, E, NB, NC);
  hipLaunchKernelGGL(place_kernel, dim3(NB), dim3(256), 0, stream, bbase, bbuf, cnt, csr, N);

  // 32 nodes per block (4 waves x NPW=8)
  int nblocks32 = (N + 31) / 32;
  hipLaunchKernelGGL((sage_layer<128, false>), dim3(nblocks32), dim3(256), 0, stream, xb, cnt,
                     csr, BfHi, BfLo, 0, b1l, (float*)nullptr, hb1, N);
  hipLaunchKernelGGL((sage_layer<64, false>), dim3(nblocks32), dim3(256), 0, stream, hb1, cnt,
                     csr, BfHi, BfLo, 32, b2l, (float*)nullptr, hb2, N);
  hipLaunchKernelGGL((sage_layer<64, true>), dim3(nblocks32), dim3(256), 0, stream, hb2, cnt,
                     csr, BfHi, BfLo, 48, b3l, h3, (unsigned short*)nullptr, N);

  hipLaunchKernelGGL(cscore_kernel, dim3(nb), dim3(256), 0, stream, clo, Wc, bc, bat, cbuf,
                     cmaxU, gcnt, N);
  hipLaunchKernelGGL(esum_kernel, dim3(nb), dim3(256), 0, stream, cbuf, bat, cmaxU, ebuf, denom,
                     N);
  int pw = (N + 63) / 64;
  int pb = (pw + 3) / 4;
  hipLaunchKernelGGL(pool_kernel, dim3(pb), dim3(256), 0, stream, ebuf, denom, gcnt, bat, h3,
                     pooledU, N);
  hipLaunchKernelGGL(final_kernel, dim3(G), dim3(64), 0, stream, pooledU, Wa1, ba1, Wa2, ba2,
                     out, G);
}

// Round 9
// 437.910 us; speedup vs baseline: 1.1897x; 1.0143x over previous
//
#include <hip/hip_runtime.h>
#include <math.h>

typedef unsigned int uint32;
typedef __attribute__((ext_vector_type(8))) short short8;
typedef __attribute__((ext_vector_type(4))) float f32x4;

#define BSH 7       // 128 nodes per bin
#define NBMAX 800   // >= ceil(N/128)
#define CHUNK 4096  // edges per chunk-block

// ---------------- helpers ----------------

__device__ __forceinline__ unsigned fkey(float f) {
  unsigned u = __float_as_uint(f);
  return (u & 0x80000000u) ? ~u : (u | 0x80000000u);
}
__device__ __forceinline__ float funkey(unsigned k) {
  unsigned u = (k & 0x80000000u) ? (k ^ 0x80000000u) : ~k;
  return __uint_as_float(u);
}
__device__ __forceinline__ unsigned short f2bf(float f) {  // RNE
  unsigned u = __float_as_uint(f);
  unsigned r = (u + 0x7FFFu + ((u >> 16) & 1u)) >> 16;
  return (unsigned short)r;
}
__device__ __forceinline__ float bf2f(unsigned short s) {
  return __uint_as_float(((unsigned)s) << 16);
}
// packed unsigned 16-bit max: 2 lanes/instr (VOP3P, gfx9+)
__device__ __forceinline__ uint32 pkmaxu(uint32 a, uint32 b) {
  uint32 d;
  asm("v_pk_max_u16 %0, %1, %2" : "=v"(d) : "v"(a), "v"(b));
  return d;
}
// sortable-key -> bf16 bits, both 16-bit halves of a dword
__device__ __forceinline__ uint32 unkey2(uint32 m) {
  uint32 t = (m >> 15) & 0x00010001u;          // 1 where key top bit set (orig >= 0)
  uint32 mask = (t * 0x7FFFu) ^ 0xFFFFFFFFu;   // ->0x8000 ; else ->0xFFFF
  return m ^ mask;
}
__device__ __forceinline__ f32x4 mfma16(short8 a, short8 b, f32x4 c) {
  return __builtin_amdgcn_mfma_f32_16x16x32_bf16(a, b, c, 0, 0, 0);
}

// ---------------- init ----------------

__global__ void init_kernel(unsigned* __restrict__ pooledU, unsigned* __restrict__ cmaxU,
                            float* __restrict__ denom, int* __restrict__ gcnt, int gh, int g) {
  int i = blockIdx.x * blockDim.x + threadIdx.x;
  if (i < gh) pooledU[i] = 0x80000000u;  // key(0.0f)
  if (i < g) { cmaxU[i] = 0u; denom[i] = 0.f; gcnt[i] = 0; }
}

// ---------------- fp32 -> sortable-key bf16 (layer-1 table) ----------------
// key(b) = (b & 0x8000) ? ~b : (b | 0x8000): u16 order == float order.

__global__ void cvt_key_kernel(const float* __restrict__ in, unsigned short* __restrict__ out,
                               int n4) {
  int i = blockIdx.x * blockDim.x + threadIdx.x;
  if (i < n4) {
    float4 v = ((const float4*)in)[i];
    ushort4 o;
    unsigned short b;
    b = f2bf(v.x); o.x = (b & 0x8000u) ? (unsigned short)~b : (unsigned short)(b | 0x8000u);
    b = f2bf(v.y); o.y = (b & 0x8000u) ? (unsigned short)~b : (unsigned short)(b | 0x8000u);
    b = f2bf(v.z); o.z = (b & 0x8000u) ? (unsigned short)~b : (unsigned short)(b | 0x8000u);
    b = f2bf(v.w); o.w = (b & 0x8000u) ? (unsigned short)~b : (unsigned short)(b | 0x8000u);
    ((ushort4*)out)[i] = o;
  }
}

// ---------------- pack weights into MFMA B-fragments (hi/lo bf16 split) -------
// B-frag layout for v_mfma_f32_16x16x32_bf16: lane l holds 8 k-consecutive
// elements: col = nt*16 + (l&15), k = ks*32 + (l>>4)*8 + e, e in [0,8).
// W stacked over K=2F: k<F -> Wl[k][col], else Wr[k-F][col].
// Groups g: L1 (F=128,KS=8): g=0..31 (nt=g>>3, ks=g&7);
//           L2 (F=64, KS=4): g=32..47; L3: g=48..63.
// out dwords: [set(hi=0,lo=1)][g][lane][p], p = e-pair. 128 KB total.

__global__ void pack_bfrag_kernel(const float* __restrict__ W1l, const float* __restrict__ W1r,
                                  const float* __restrict__ W2l, const float* __restrict__ W2r,
                                  const float* __restrict__ W3l, const float* __restrict__ W3r,
                                  uint32* __restrict__ out) {
  int i = blockIdx.x * blockDim.x + threadIdx.x;
  if (i >= 32768) return;
  int set = i >> 14;
  int r = i & 16383;
  int g = r >> 8;
  int lane = (r >> 2) & 63;
  int p = r & 3;
  const float *Wl, *Wr;
  int F, nt, ks;
  if (g < 32) {
    F = 128; Wl = W1l; Wr = W1r; nt = g >> 3; ks = g & 7;
  } else if (g < 48) {
    F = 64; Wl = W2l; Wr = W2r; int q = g - 32; nt = q >> 2; ks = q & 3;
  } else {
    F = 64; Wl = W3l; Wr = W3r; int q = g - 48; nt = q >> 2; ks = q & 3;
  }
  int col = nt * 16 + (lane & 15);
  int k0 = ks * 32 + ((lane >> 4) << 3) + 2 * p;
  float w0 = (k0 < F) ? Wl[k0 * 64 + col] : Wr[(k0 - F) * 64 + col];
  int k1 = k0 + 1;
  float w1 = (k1 < F) ? Wl[k1 * 64 + col] : Wr[(k1 - F) * 64 + col];
  if (set) {  // lo = residual after bf16(hi)
    w0 -= bf2f(f2bf(w0));
    w1 -= bf2f(f2bf(w1));
  }
  out[i] = ((uint32)f2bf(w1) << 16) | (uint32)f2bf(w0);
}

// ---------------- CSR build: zero-global-atomic counting sort ----------------
//  hist:   per-chunk per-bin counts (LDS atomics only), hist[b][c]
//  rowscan: exclusive scan of each bin row  -> per-(chunk,bin) offset; bsum[b]
//  binscan: exclusive scan of bin totals    -> bbase[b] (bbase[NB]=E)
//  bfill:  re-read edges, place packed recs at bbase[b]+hist[b][c]+i (LDS cursors)
//  place:  per-bin block: LDS node counters, scatter into 32KB L2-resident CSR
//          window. Node n's in-edges at csr[n*64 .. n*64+cnt[n]).

__global__ void hist_kernel(const int* __restrict__ dst, int* __restrict__ hist,
                            int E, int NB, int NC) {
  __shared__ int lcnt[NBMAX];
  int t = threadIdx.x, c = blockIdx.x;
  for (int i = t; i < NB; i += 256) lcnt[i] = 0;
  __syncthreads();
  int e0 = c * CHUNK, e1 = min(e0 + CHUNK, E);
  for (int e = e0 + t; e < e1; e += 256) atomicAdd(&lcnt[dst[e] >> BSH], 1);
  __syncthreads();
  for (int i = t; i < NB; i += 256) hist[(size_t)i * NC + c] = lcnt[i];
}

__global__ void rowscan_kernel(int* __restrict__ hist, int* __restrict__ bsum, int NB, int NC) {
  int wv = blockIdx.x * 4 + (threadIdx.x >> 6);
  int lane = threadIdx.x & 63;
  if (wv >= NB) return;
  int* row = hist + (size_t)wv * NC;
  int run = 0;
  for (int c = 0; c < NC; c += 64) {
    int idx = c + lane;
    int v = (idx < NC) ? row[idx] : 0;
    int incl = v;
#pragma unroll
    for (int off = 1; off < 64; off <<= 1) {
      int tt = __shfl_up(incl, off);
      if (lane >= off) incl += tt;
    }
    int tot = __shfl(incl, 63);
    if (idx < NC) row[idx] = run + incl - v;
    run += tot;
  }
  if (lane == 0) bsum[wv] = run;
}

__global__ void binscan_kernel(const int* __restrict__ bsum, int* __restrict__ bbase, int NB) {
  int lane = threadIdx.x;  // block = 64
  int run = 0;
  for (int c = 0; c < NB; c += 64) {
    int idx = c + lane;
    int v = (idx < NB) ? bsum[idx] : 0;
    int incl = v;
#pragma unroll
    for (int off = 1; off < 64; off <<= 1) {
      int tt = __shfl_up(incl, off);
      if (lane >= off) incl += tt;
    }
    if (idx < NB) bbase[idx] = run + incl - v;
    run += __shfl(incl, 63);
  }
  if (lane == 0) bbase[NB] = run;
}

__global__ void bfill_kernel(const int* __restrict__ src, const int* __restrict__ dst,
                             const int* __restrict__ hist, const int* __restrict__ bbase,
                             uint32* __restrict__ bbuf, int E, int NB, int NC) {
  __shared__ int lcur[NBMAX];
  int t = threadIdx.x, c = blockIdx.x;
  for (int i = t; i < NB; i += 256) lcur[i] = bbase[i] + hist[(size_t)i * NC + c];
  __syncthreads();
  int e0 = c * CHUNK, e1 = min(e0 + CHUNK, E);
  for (int e = e0 + t; e < e1; e += 256) {
    int d = dst[e], s = src[e];
    int b = d >> BSH;
    int pos = atomicAdd(&lcur[b], 1);
    bbuf[pos] = ((uint32)s << BSH) | (uint32)(d & ((1 << BSH) - 1));
  }
}

__global__ void place_kernel(const int* __restrict__ bbase, const uint32* __restrict__ bbuf,
                             int* __restrict__ cnt, int* __restrict__ csr, int N) {
  __shared__ int lcnt[1 << BSH];
  int b = blockIdx.x, t = threadIdx.x;
  for (int i = t; i < (1 << BSH); i += 256) lcnt[i] = 0;
  __syncthreads();
  int s0 = bbase[b], s1 = bbase[b + 1];
  for (int i = s0 + t; i < s1; i += 256) {
    uint32 rec = bbuf[i];
    int dl = rec & ((1 << BSH) - 1);
    int s = (int)(rec >> BSH);
    int pos = atomicAdd(&lcnt[dl], 1);
    if (pos < 64) csr[(((b << BSH) + dl) << 6) + pos] = s;
  }
  __syncthreads();
  int base = b << BSH;
  for (int i = t; i < (1 << BSH); i += 256) {
    int d = base + i;
    if (d < N) cnt[d] = min(lcnt[i], 64);
  }
}

// ---------------- fused SAGE layer ----------------
// Gather phase: R6-proven addressing (pkmaxu on raw dwords, clamped slot
// indices, dual-edge half-wave h-packing, ZERO accumulator floor -- the
// identity for unsigned-max over both sortable keys and post-ReLU bf16 bits;
// R8's 0xFC00 "-inf" floor was an f16 leftover and u16-dominates everything)
// with TWO NODES INTERLEAVED per iteration: independent accumulators +
// clamped index streams in lock-step (trip count = max of pair degrees;
// shorter node's slots clamp to its last real edge -> benign L1-hot dups).
// Halves serialized latency chains per wave (8 -> 4). Deg-0: loads redirect
// to the node's own row (wave-uniform) and the accumulator is zeroed after
// the loop. Results bit-identical to R6. Matmul phase unchanged.

template <int F, bool OUT_F32>
__global__ void __launch_bounds__(256, 2) sage_layer(
    const unsigned short* __restrict__ xg,  // bf16/key table [nn,F]
    const int* __restrict__ cnt, const int* __restrict__ csr,
    const short8* __restrict__ BfHi, const short8* __restrict__ BfLo, int loff,
    const float* __restrict__ bl, float* __restrict__ outf,
    unsigned short* __restrict__ outb, int nn) {
  constexpr int NPW = 8;
  constexpr int PAD = F + 4;  // dwords per A row (K=2F bf16 = F dwords) + pad
  constexpr int KS = F / 16;  // k-steps of 32 over K=2F
  constexpr bool KEYED = (F == 128);  // layer-1 table is key-transformed
  const int lane = threadIdx.x & 63;
  const int wid = threadIdx.x >> 6;
  const int c = lane & 31;  // feature-chunk index within a row
  const int h = lane >> 5;  // half-wave: which of the 2 packed edges
  const int blk = blockIdx.x * 32;
  __shared__ uint32 Abuf[32][PAD];

  for (int jp = 0; jp < NPW; jp += 2) {
    const int nla = wid * NPW + jp, nlb = nla + 1;
    const int na = blk + nla, nb = blk + nlb;
    const int sa = (na < nn) ? na : 0;  // safe row ids for sanitized loads
    const int sb = (nb < nn) ? nb : 0;
    int dga = 0, dgb = 0;
    if (na < nn) dga = cnt[na];
    if (nb < nn) dgb = cnt[nb];
    if (dga > 64) dga = 64;
    if (dgb > 64) dgb = 64;
    const int KM = max(dga, dgb);

    if constexpr (F == 128) {
      uint32 a01 = 0u, a23 = 0u, b01 = 0u, b23 = 0u, sva = 0u, svb = 0u;
      if (na < nn) sva = *(const uint32*)(xg + ((size_t)na << 7) + 2 * lane);
      if (nb < nn) svb = *(const uint32*)(xg + ((size_t)nb << 7) + 2 * lane);
      if (KM > 0) {
        // floor stays 0u: identity for u16-max over keys (min key) [R8 errata]
        const int k0a = na << 6, kma = k0a + max(dga, 1) - 1;
        const int k0b = nb << 6, kmb = k0b + max(dgb, 1) - 1;
#define LD128(i) (*(const uint2*)(xg + ((size_t)(i) << 7) + 4 * c))
        for (int kk = 0; kk < KM; kk += 8) {
          int ia0 = csr[min(k0a + kk + 0 + h, kma)], ia1 = csr[min(k0a + kk + 2 + h, kma)];
          int ia2 = csr[min(k0a + kk + 4 + h, kma)], ia3 = csr[min(k0a + kk + 6 + h, kma)];
          int ib0 = csr[min(k0b + kk + 0 + h, kmb)], ib1 = csr[min(k0b + kk + 2 + h, kmb)];
          int ib2 = csr[min(k0b + kk + 4 + h, kmb)], ib3 = csr[min(k0b + kk + 6 + h, kmb)];
          if (!dga) { ia0 = sa; ia1 = sa; ia2 = sa; ia3 = sa; }  // wave-uniform
          if (!dgb) { ib0 = sb; ib1 = sb; ib2 = sb; ib3 = sb; }
          uint2 A0 = LD128(ia0), A1 = LD128(ia1), A2 = LD128(ia2), A3 = LD128(ia3);
          uint2 B0 = LD128(ib0), B1 = LD128(ib1), B2 = LD128(ib2), B3 = LD128(ib3);
          a01 = pkmaxu(a01, pkmaxu(pkmaxu(A0.x, A1.x), pkmaxu(A2.x, A3.x)));
          a23 = pkmaxu(a23, pkmaxu(pkmaxu(A0.y, A1.y), pkmaxu(A2.y, A3.y)));
          b01 = pkmaxu(b01, pkmaxu(pkmaxu(B0.x, B1.x), pkmaxu(B2.x, B3.x)));
          b23 = pkmaxu(b23, pkmaxu(pkmaxu(B0.y, B1.y), pkmaxu(B2.y, B3.y)));
        }
#undef LD128
        a01 = pkmaxu(a01, (uint32)__shfl_xor((int)a01, 32));
        a23 = pkmaxu(a23, (uint32)__shfl_xor((int)a23, 32));
        b01 = pkmaxu(b01, (uint32)__shfl_xor((int)b01, 32));
        b23 = pkmaxu(b23, (uint32)__shfl_xor((int)b23, 32));
        if constexpr (KEYED) {
          a01 = unkey2(a01); a23 = unkey2(a23);
          b01 = unkey2(b01); b23 = unkey2(b23);
        }
        if (!dga) { a01 = 0u; a23 = 0u; }  // empty neighborhood -> 0
        if (!dgb) { b01 = 0u; b23 = 0u; }
      }
      if (h == 0) {  // agg (exact bf16) at k=[0,F)
        uint2 mm;
        mm.x = a01; mm.y = a23;
        *(uint2*)&Abuf[nla][2 * c] = mm;
        mm.x = b01; mm.y = b23;
        *(uint2*)&Abuf[nlb][2 * c] = mm;
      }
      Abuf[nla][64 + lane] = KEYED ? unkey2(sva) : sva;  // self at k=[F,2F)
      Abuf[nlb][64 + lane] = KEYED ? unkey2(svb) : svb;
    } else {
      uint32 a01 = 0u, b01 = 0u, sva = 0u, svb = 0u;
      if (h == 0) {
        if (na < nn) sva = *(const uint32*)(xg + ((size_t)na << 6) + 2 * c);
        if (nb < nn) svb = *(const uint32*)(xg + ((size_t)nb << 6) + 2 * c);
      }
      if (KM > 0) {
        // floor stays 0u: identity for u16-max over post-ReLU bf16 bits
        const int k0a = na << 6, kma = k0a + max(dga, 1) - 1;
        const int k0b = nb << 6, kmb = k0b + max(dgb, 1) - 1;
#define LD64(i) (*(const uint32*)(xg + ((size_t)(i) << 6) + 2 * c))
        for (int kk = 0; kk < KM; kk += 8) {
          int ia0 = csr[min(k0a + kk + 0 + h, kma)], ia1 = csr[min(k0a + kk + 2 + h, kma)];
          int ia2 = csr[min(k0a + kk + 4 + h, kma)], ia3 = csr[min(k0a + kk + 6 + h, kma)];
          int ib0 = csr[min(k0b + kk + 0 + h, kmb)], ib1 = csr[min(k0b + kk + 2 + h, kmb)];
          int ib2 = csr[min(k0b + kk + 4 + h, kmb)], ib3 = csr[min(k0b + kk + 6 + h, kmb)];
          if (!dga) { ia0 = sa; ia1 = sa; ia2 = sa; ia3 = sa; }
          if (!dgb) { ib0 = sb; ib1 = sb; ib2 = sb; ib3 = sb; }
          uint32 A0 = LD64(ia0), A1 = LD64(ia1), A2 = LD64(ia2), A3 = LD64(ia3);
          uint32 B0 = LD64(ib0), B1 = LD64(ib1), B2 = LD64(ib2), B3 = LD64(ib3);
          a01 = pkmaxu(a01, pkmaxu(pkmaxu(A0, A1), pkmaxu(A2, A3)));
          b01 = pkmaxu(b01, pkmaxu(pkmaxu(B0, B1), pkmaxu(B2, B3)));
        }
#undef LD64
        a01 = pkmaxu(a01, (uint32)__shfl_xor((int)a01, 32));
        b01 = pkmaxu(b01, (uint32)__shfl_xor((int)b01, 32));
        if (!dga) a01 = 0u;
        if (!dgb) b01 = 0u;
      }
      if (h == 0) {
        Abuf[nla][c] = a01;       // agg at k=[0,F)
        Abuf[nla][32 + c] = sva;  // self at k=[F,2F)
        Abuf[nlb][c] = b01;
        Abuf[nlb][32 + c] = svb;
      }
    }
  }
  __syncthreads();  // A matrix is block-shared by the MFMA phase

  // ---- MFMA matmul: C[32][64] = A[32][2F] * Wstack[2F][64] + b ----
  const int l15 = lane & 15, lk = lane >> 4;
  const int mt = wid & 1;           // m-tile (rows mt*16..mt*16+15)
  const int ntb = (wid >> 1) << 1;  // this wave's 2 n-tiles: ntb, ntb+1
  const int arow = mt * 16 + l15;
  float bb0 = bl[ntb * 16 + l15], bb1 = bl[ntb * 16 + 16 + l15];
  f32x4 acc0 = {bb0, bb0, bb0, bb0};
  f32x4 acc1 = {bb1, bb1, bb1, bb1};
  const int gb0 = (loff + (ntb + 0) * KS) * 64 + lane;
  const int gb1 = (loff + (ntb + 1) * KS) * 64 + lane;
#pragma unroll 2
  for (int ks = 0; ks < KS; ++ks) {
    short8 a = *(const short8*)&Abuf[arow][ks * 16 + lk * 4];
    short8 bh0 = BfHi[gb0 + ks * 64];
    short8 bl0 = BfLo[gb0 + ks * 64];
    short8 bh1 = BfHi[gb1 + ks * 64];
    short8 bl1 = BfLo[gb1 + ks * 64];
    acc0 = mfma16(a, bh0, acc0);
    acc0 = mfma16(a, bl0, acc0);
    acc1 = mfma16(a, bh1, acc1);
    acc1 = mfma16(a, bl1, acc1);
  }
  // C layout: col = lane&15, row = (lane>>4)*4 + j
#pragma unroll
  for (int j = 0; j < 4; ++j) {
    int node = blk + mt * 16 + lk * 4 + j;
    if (node < nn) {
      float r0 = fmaxf(acc0[j], 0.f);
      float r1 = fmaxf(acc1[j], 0.f);
      if constexpr (OUT_F32) {
        outf[(size_t)node * 64 + ntb * 16 + l15] = r0;
        outf[(size_t)node * 64 + ntb * 16 + 16 + l15] = r1;
      } else {
        outb[(size_t)node * 64 + ntb * 16 + l15] = f2bf(r0);
        outb[(size_t)node * 64 + ntb * 16 + 16 + l15] = f2bf(r1);
      }
    }
  }
}

// ---------------- pooling tail ----------------

__global__ void cscore_kernel(const float* __restrict__ clo, const float* __restrict__ Wc,
                              const float* __restrict__ bc, const int* __restrict__ bat,
                              float* __restrict__ cbuf, unsigned* __restrict__ cmaxU,
                              int* __restrict__ gcnt, int n) {
  int i = blockIdx.x * blockDim.x + threadIdx.x;
  int lane = threadIdx.x & 63;
  float cv = -INFINITY;
  int g = -1;
  if (i < n) {
    const float4* row = (const float4*)(clo + (size_t)i * 16);
    float4 r0 = row[0], r1 = row[1], r2 = row[2], r3 = row[3];
    cv = bc[0];
    cv += r0.x * Wc[0] + r0.y * Wc[1] + r0.z * Wc[2] + r0.w * Wc[3];
    cv += r1.x * Wc[4] + r1.y * Wc[5] + r1.z * Wc[6] + r1.w * Wc[7];
    cv += r2.x * Wc[8] + r2.y * Wc[9] + r2.z * Wc[10] + r2.w * Wc[11];
    cv += r3.x * Wc[12] + r3.y * Wc[13] + r3.z * Wc[14] + r3.w * Wc[15];
    cbuf[i] = cv;
    g = bat[i];
  }
  int g0 = __shfl(g, 0), g63 = __shfl(g, 63);
  if (g0 >= 0 && g0 == g63) {  // whole wave in one graph (batch sorted)
    float m = cv;
#pragma unroll
    for (int off = 32; off; off >>= 1) m = fmaxf(m, __shfl_down(m, off));
    if (lane == 0) {
      atomicMax(&cmaxU[g0], fkey(m));
      atomicAdd(&gcnt[g0], 64);
    }
  } else if (g >= 0) {
    atomicMax(&cmaxU[g], fkey(cv));
    atomicAdd(&gcnt[g], 1);
  }
}

__global__ void esum_kernel(const float* __restrict__ cbuf, const int* __restrict__ bat,
                            const unsigned* __restrict__ cmaxU, float* __restrict__ ebuf,
                            float* __restrict__ denom, int n) {
  int i = blockIdx.x * blockDim.x + threadIdx.x;
  int lane = threadIdx.x & 63;
  float ev = 0.f;
  int g = -1;
  if (i < n) {
    g = bat[i];
    float cm = funkey(cmaxU[g]);
    ev = expf(cbuf[i] - cm);
    ebuf[i] = ev;
  }
  int g0 = __shfl(g, 0), g63 = __shfl(g, 63);
  if (g0 >= 0 && g0 == g63) {
    float s = ev;
#pragma unroll
    for (int off = 32; off; off >>= 1) s += __shfl_down(s, off);
    if (lane == 0) atomicAdd(&denom[g0], s);
  } else if (g >= 0) {
    atomicAdd(&denom[g], ev);
  }
}

__global__ void pool_kernel(const float* __restrict__ ebuf, const float* __restrict__ denom,
                            const int* __restrict__ gcnt, const int* __restrict__ bat,
                            const float* __restrict__ h3, unsigned* __restrict__ pooledU,
                            int n) {
  const int CH = 64;
  int wave = (blockIdx.x * blockDim.x + threadIdx.x) >> 6;
  int lane = threadIdx.x & 63;
  int nb = wave * CH;
  if (nb >= n) return;
  int ne = min(nb + CH, n);
  int curg = bat[nb];
  float factor = (float)gcnt[curg] / denom[curg];
  float lmax = -INFINITY;
  for (int nd = nb; nd < ne; ++nd) {
    int g = bat[nd];
    if (g != curg) {
      atomicMax(&pooledU[(size_t)curg * 64 + lane], fkey(lmax));
      curg = g;
      factor = (float)gcnt[g] / denom[g];
      lmax = -INFINITY;
    }
    float v = ebuf[nd] * factor * h3[(size_t)nd * 64 + lane];
    lmax = fmaxf(lmax, v);
  }
  atomicMax(&pooledU[(size_t)curg * 64 + lane], fkey(lmax));
}

__global__ void final_kernel(const unsigned* __restrict__ pooledU, const float* __restrict__ Wa1,
                             const float* __restrict__ ba1, const float* __restrict__ Wa2,
                             const float* __restrict__ ba2, float* __restrict__ out, int G) {
  int g = blockIdx.x;
  int lane = threadIdx.x;  // block = 64
  float v = funkey(pooledU[(size_t)g * 64 + lane]);
  if (!isfinite(v)) v = 0.f;
  float outv = 0.f;
#pragma unroll
  for (int j = 0; j < 16; ++j) {
    float psum = v * Wa1[lane * 16 + j];
#pragma unroll
    for (int off = 32; off; off >>= 1) psum += __shfl_down(psum, off);
    if (lane == 0) outv += fmaxf(psum + ba1[j], 0.f) * Wa2[j];
  }
  if (lane == 0) out[g] = outv + ba2[0];
}

// ---------------- launch ----------------

static inline size_t alignup(size_t x) { return (x + 255) & ~(size_t)255; }

extern "C" void kernel_launch(void* const* d_in, const int* in_sizes, int n_in,
                              void* d_out, int out_size, void* d_ws, size_t ws_size,
                              hipStream_t stream) {
  const float* x = (const float*)d_in[0];
  const int* ei = (const int*)d_in[1];
  const int* bat = (const int*)d_in[2];
  const float* clo = (const float*)d_in[3];
  const float* W1l = (const float*)d_in[4];
  const float* b1l = (const float*)d_in[5];
  const float* W1r = (const float*)d_in[6];
  const float* W2l = (const float*)d_in[7];
  const float* b2l = (const float*)d_in[8];
  const float* W2r = (const float*)d_in[9];
  const float* W3l = (const float*)d_in[10];
  const float* b3l = (const float*)d_in[11];
  const float* W3r = (const float*)d_in[12];
  const float* Wc = (const float*)d_in[13];
  const float* bc = (const float*)d_in[14];
  const float* Wa1 = (const float*)d_in[15];
  const float* ba1 = (const float*)d_in[16];
  const float* Wa2 = (const float*)d_in[17];
  const float* ba2 = (const float*)d_in[18];
  float* out = (float*)d_out;

  const int N = in_sizes[2];
  const int E = in_sizes[1] / 2;
  const int G = out_size;
  const int FIN = in_sizes[0] / N;  // 128

  char* p = (char*)d_ws;
  auto carve = [&](size_t bytes) {
    char* r = p;
    p += alignup(bytes);
    return r;
  };
  const int NB = (N + (1 << BSH) - 1) >> BSH;  // bins
  const int NC = (E + CHUNK - 1) / CHUNK;      // chunks
  int* cnt = (int*)carve((size_t)N * 4);
  int* csr = (int*)carve((size_t)N * 64 * 4);  // padded slots, 256 B per node
  unsigned short* xb = (unsigned short*)carve((size_t)N * FIN * 2);  // key table; h3 overlay
  unsigned short* hb1 = (unsigned short*)carve((size_t)N * 64 * 2);
  unsigned short* hb2 = (unsigned short*)carve((size_t)N * 64 * 2);
  float* cbuf = (float*)carve((size_t)N * 4);
  float* ebuf = (float*)carve((size_t)N * 4);
  unsigned* cmaxU = (unsigned*)carve((size_t)G * 4);
  float* denom = (float*)carve((size_t)G * 4);
  int* gcnt = (int*)carve((size_t)G * 4);
  unsigned* pooledU = (unsigned*)carve((size_t)G * 64 * 4);
  uint32* Bfrag = (uint32*)carve((size_t)32768 * 4);  // MFMA B-fragments hi+lo
  int* hist = (int*)carve((size_t)NB * NC * 4);
  int* bsum = (int*)carve((size_t)NB * 4);
  int* bbase = (int*)carve((size_t)(NB + 1) * 4);
  uint32* bbuf = (uint32*)carve((size_t)E * 4);  // exactly-compacted records
  float* h3 = (float*)xb;  // xb (N*128*2 B) dead after layer1; h3 = N*64*4 B fits exactly

  const short8* BfHi = (const short8*)Bfrag;
  const short8* BfLo = (const short8*)(Bfrag + 16384);

  const int* srcv = ei;
  const int* dstv = ei + E;

  int nb = (N + 255) / 256;
  hipLaunchKernelGGL(init_kernel, dim3((G * 64 + 255) / 256), dim3(256), 0, stream, pooledU,
                     cmaxU, denom, gcnt, G * 64, G);
  int ncvt = (N * FIN) / 4;
  hipLaunchKernelGGL(cvt_key_kernel, dim3((ncvt + 255) / 256), dim3(256), 0, stream, x, xb,
                     ncvt);
  hipLaunchKernelGGL(pack_bfrag_kernel, dim3(128), dim3(256), 0, stream, W1l, W1r, W2l, W2r,
                     W3l, W3r, Bfrag);
  hipLaunchKernelGGL(hist_kernel, dim3(NC), dim3(256), 0, stream, dstv, hist, E, NB, NC);
  hipLaunchKernelGGL(rowscan_kernel, dim3((NB + 3) / 4), dim3(256), 0, stream, hist, bsum, NB,
                     NC);
  hipLaunchKernelGGL(binscan_kernel, dim3(1), dim3(64), 0, stream, bsum, bbase, NB);
  hipLaunchKernelGGL(bfill_kernel, dim3(NC), dim3(256), 0, stream, srcv, dstv, hist, bbase,
                     bbuf, E, NB, NC);
  hipLaunchKernelGGL(place_kernel, dim3(NB), dim3(256), 0, stream, bbase, bbuf, cnt, csr, N);

  // 32 nodes per block (4 waves x NPW=8)
  int nblocks32 = (N + 31) / 32;
  hipLaunchKernelGGL((sage_layer<128, false>), dim3(nblocks32), dim3(256), 0, stream, xb, cnt,
                     csr, BfHi, BfLo, 0, b1l, (float*)nullptr, hb1, N);
  hipLaunchKernelGGL((sage_layer<64, false>), dim3(nblocks32), dim3(256), 0, stream, hb1, cnt,
                     csr, BfHi, BfLo, 32, b2l, (float*)nullptr, hb2, N);
  hipLaunchKernelGGL((sage_layer<64, true>), dim3(nblocks32), dim3(256), 0, stream, hb2, cnt,
                     csr, BfHi, BfLo, 48, b3l, h3, (unsigned short*)nullptr, N);

  hipLaunchKernelGGL(cscore_kernel, dim3(nb), dim3(256), 0, stream, clo, Wc, bc, bat, cbuf,
                     cmaxU, gcnt, N);
  hipLaunchKernelGGL(esum_kernel, dim3(nb), dim3(256), 0, stream, cbuf, bat, cmaxU, ebuf, denom,
                     N);
  int pw = (N + 63) / 64;
  int pb = (pw + 3) / 4;
  hipLaunchKernelGGL(pool_kernel, dim3(pb), dim3(256), 0, stream, ebuf, denom, gcnt, bat, h3,
                     pooledU, N);
  hipLaunchKernelGGL(final_kernel, dim3(G), dim3(64), 0, stream, pooledU, Wa1, ba1, Wa2, ba2,
                     out, G);
}

// Round 10
// 436.829 us; speedup vs baseline: 1.1926x; 1.0025x over previous
//
#include <hip/hip_runtime.h>
#include <math.h>

typedef unsigned int uint32;
typedef __attribute__((ext_vector_type(8))) short short8;
typedef __attribute__((ext_vector_type(4))) float f32x4;

#define BSH 7       // 128 nodes per bin
#define NBMAX 800   // >= ceil(N/128)
#define CHUNK 4096  // edges per chunk-block

// ---------------- helpers ----------------

__device__ __forceinline__ unsigned fkey(float f) {
  unsigned u = __float_as_uint(f);
  return (u & 0x80000000u) ? ~u : (u | 0x80000000u);
}
__device__ __forceinline__ float funkey(unsigned k) {
  unsigned u = (k & 0x80000000u) ? (k ^ 0x80000000u) : ~k;
  return __uint_as_float(u);
}
__device__ __forceinline__ unsigned short f2bf(float f) {  // RNE
  unsigned u = __float_as_uint(f);
  unsigned r = (u + 0x7FFFu + ((u >> 16) & 1u)) >> 16;
  return (unsigned short)r;
}
__device__ __forceinline__ float bf2f(unsigned short s) {
  return __uint_as_float(((unsigned)s) << 16);
}
// packed unsigned 16-bit max: 2 lanes/instr (VOP3P, gfx9+)
__device__ __forceinline__ uint32 pkmaxu(uint32 a, uint32 b) {
  uint32 d;
  asm("v_pk_max_u16 %0, %1, %2" : "=v"(d) : "v"(a), "v"(b));
  return d;
}
// sortable-key -> bf16 bits, both 16-bit halves of a dword
__device__ __forceinline__ uint32 unkey2(uint32 m) {
  uint32 t = (m >> 15) & 0x00010001u;          // 1 where key top bit set (orig >= 0)
  uint32 mask = (t * 0x7FFFu) ^ 0xFFFFFFFFu;   // ->0x8000 ; else ->0xFFFF
  return m ^ mask;
}
__device__ __forceinline__ f32x4 mfma16(short8 a, short8 b, f32x4 c) {
  return __builtin_amdgcn_mfma_f32_16x16x32_bf16(a, b, c, 0, 0, 0);
}

// ---------------- init ----------------

__global__ void init_kernel(unsigned* __restrict__ pooledU, unsigned* __restrict__ cmaxU,
                            float* __restrict__ denom, int* __restrict__ gcnt, int gh, int g) {
  int i = blockIdx.x * blockDim.x + threadIdx.x;
  if (i < gh) pooledU[i] = 0x80000000u;  // key(0.0f)
  if (i < g) { cmaxU[i] = 0u; denom[i] = 0.f; gcnt[i] = 0; }
}

// ---------------- fp32 -> sortable-key bf16 (layer-1 table) ----------------
// key(b) = (b & 0x8000) ? ~b : (b | 0x8000): u16 order == float order.

__global__ void cvt_key_kernel(const float* __restrict__ in, unsigned short* __restrict__ out,
                               int n4) {
  int i = blockIdx.x * blockDim.x + threadIdx.x;
  if (i < n4) {
    float4 v = ((const float4*)in)[i];
    ushort4 o;
    unsigned short b;
    b = f2bf(v.x); o.x = (b & 0x8000u) ? (unsigned short)~b : (unsigned short)(b | 0x8000u);
    b = f2bf(v.y); o.y = (b & 0x8000u) ? (unsigned short)~b : (unsigned short)(b | 0x8000u);
    b = f2bf(v.z); o.z = (b & 0x8000u) ? (unsigned short)~b : (unsigned short)(b | 0x8000u);
    b = f2bf(v.w); o.w = (b & 0x8000u) ? (unsigned short)~b : (unsigned short)(b | 0x8000u);
    ((ushort4*)out)[i] = o;
  }
}

// ---------------- pack weights into MFMA B-fragments (hi/lo bf16 split) -------
// B-frag layout for v_mfma_f32_16x16x32_bf16: lane l holds 8 k-consecutive
// elements: col = nt*16 + (l&15), k = ks*32 + (l>>4)*8 + e, e in [0,8).
// W stacked over K=2F: k<F -> Wl[k][col], else Wr[k-F][col].
// Groups g: L1 (F=128,KS=8): g=0..31 (nt=g>>3, ks=g&7);
//           L2 (F=64, KS=4): g=32..47; L3: g=48..63.
// out dwords: [set(hi=0,lo=1)][g][lane][p], p = e-pair. 128 KB total.

__global__ void pack_bfrag_kernel(const float* __restrict__ W1l, const float* __restrict__ W1r,
                                  const float* __restrict__ W2l, const float* __restrict__ W2r,
                                  const float* __restrict__ W3l, const float* __restrict__ W3r,
                                  uint32* __restrict__ out) {
  int i = blockIdx.x * blockDim.x + threadIdx.x;
  if (i >= 32768) return;
  int set = i >> 14;
  int r = i & 16383;
  int g = r >> 8;
  int lane = (r >> 2) & 63;
  int p = r & 3;
  const float *Wl, *Wr;
  int F, nt, ks;
  if (g < 32) {
    F = 128; Wl = W1l; Wr = W1r; nt = g >> 3; ks = g & 7;
  } else if (g < 48) {
    F = 64; Wl = W2l; Wr = W2r; int q = g - 32; nt = q >> 2; ks = q & 3;
  } else {
    F = 64; Wl = W3l; Wr = W3r; int q = g - 48; nt = q >> 2; ks = q & 3;
  }
  int col = nt * 16 + (lane & 15);
  int k0 = ks * 32 + ((lane >> 4) << 3) + 2 * p;
  float w0 = (k0 < F) ? Wl[k0 * 64 + col] : Wr[(k0 - F) * 64 + col];
  int k1 = k0 + 1;
  float w1 = (k1 < F) ? Wl[k1 * 64 + col] : Wr[(k1 - F) * 64 + col];
  if (set) {  // lo = residual after bf16(hi)
    w0 -= bf2f(f2bf(w0));
    w1 -= bf2f(f2bf(w1));
  }
  out[i] = ((uint32)f2bf(w1) << 16) | (uint32)f2bf(w0);
}

// ---------------- CSR build: zero-global-atomic counting sort ----------------
//  hist:   per-chunk per-bin counts (LDS atomics only), hist[b][c]
//  rowscan: exclusive scan of each bin row  -> per-(chunk,bin) offset; bsum[b]
//  binscan: exclusive scan of bin totals    -> bbase[b] (bbase[NB]=E)
//  bfill:  re-read edges, place packed recs at bbase[b]+hist[b][c]+i (LDS cursors)
//  place:  per-bin block: LDS node counters, scatter into 32KB L2-resident CSR
//          window. Node n's in-edges at csr[n*64 .. n*64+cnt[n]).

__global__ void hist_kernel(const int* __restrict__ dst, int* __restrict__ hist,
                            int E, int NB, int NC) {
  __shared__ int lcnt[NBMAX];
  int t = threadIdx.x, c = blockIdx.x;
  for (int i = t; i < NB; i += 256) lcnt[i] = 0;
  __syncthreads();
  int e0 = c * CHUNK, e1 = min(e0 + CHUNK, E);
  for (int e = e0 + t; e < e1; e += 256) atomicAdd(&lcnt[dst[e] >> BSH], 1);
  __syncthreads();
  for (int i = t; i < NB; i += 256) hist[(size_t)i * NC + c] = lcnt[i];
}

__global__ void rowscan_kernel(int* __restrict__ hist, int* __restrict__ bsum, int NB, int NC) {
  int wv = blockIdx.x * 4 + (threadIdx.x >> 6);
  int lane = threadIdx.x & 63;
  if (wv >= NB) return;
  int* row = hist + (size_t)wv * NC;
  int run = 0;
  for (int c = 0; c < NC; c += 64) {
    int idx = c + lane;
    int v = (idx < NC) ? row[idx] : 0;
    int incl = v;
#pragma unroll
    for (int off = 1; off < 64; off <<= 1) {
      int tt = __shfl_up(incl, off);
      if (lane >= off) incl += tt;
    }
    int tot = __shfl(incl, 63);
    if (idx < NC) row[idx] = run + incl - v;
    run += tot;
  }
  if (lane == 0) bsum[wv] = run;
}

__global__ void binscan_kernel(const int* __restrict__ bsum, int* __restrict__ bbase, int NB) {
  int lane = threadIdx.x;  // block = 64
  int run = 0;
  for (int c = 0; c < NB; c += 64) {
    int idx = c + lane;
    int v = (idx < NB) ? bsum[idx] : 0;
    int incl = v;
#pragma unroll
    for (int off = 1; off < 64; off <<= 1) {
      int tt = __shfl_up(incl, off);
      if (lane >= off) incl += tt;
    }
    if (idx < NB) bbase[idx] = run + incl - v;
    run += __shfl(incl, 63);
  }
  if (lane == 0) bbase[NB] = run;
}

__global__ void bfill_kernel(const int* __restrict__ src, const int* __restrict__ dst,
                             const int* __restrict__ hist, const int* __restrict__ bbase,
                             uint32* __restrict__ bbuf, int E, int NB, int NC) {
  __shared__ int lcur[NBMAX];
  int t = threadIdx.x, c = blockIdx.x;
  for (int i = t; i < NB; i += 256) lcur[i] = bbase[i] + hist[(size_t)i * NC + c];
  __syncthreads();
  int e0 = c * CHUNK, e1 = min(e0 + CHUNK, E);
  for (int e = e0 + t; e < e1; e += 256) {
    int d = dst[e], s = src[e];
    int b = d >> BSH;
    int pos = atomicAdd(&lcur[b], 1);
    bbuf[pos] = ((uint32)s << BSH) | (uint32)(d & ((1 << BSH) - 1));
  }
}

__global__ void place_kernel(const int* __restrict__ bbase, const uint32* __restrict__ bbuf,
                             int* __restrict__ cnt, int* __restrict__ csr, int N) {
  __shared__ int lcnt[1 << BSH];
  int b = blockIdx.x, t = threadIdx.x;
  for (int i = t; i < (1 << BSH); i += 256) lcnt[i] = 0;
  __syncthreads();
  int s0 = bbase[b], s1 = bbase[b + 1];
  for (int i = s0 + t; i < s1; i += 256) {
    uint32 rec = bbuf[i];
    int dl = rec & ((1 << BSH) - 1);
    int s = (int)(rec >> BSH);
    int pos = atomicAdd(&lcnt[dl], 1);
    if (pos < 64) csr[(((b << BSH) + dl) << 6) + pos] = s;
  }
  __syncthreads();
  int base = b << BSH;
  for (int i = t; i < (1 << BSH); i += 256) {
    int d = base + i;
    if (d < N) cnt[d] = min(lcnt[i], 64);
  }
}

// ---------------- fused SAGE layer ----------------
// Gather phase: R9-proven structure (pkmaxu raw-dword max, zero floor,
// clamped slot indices via max(dg,1)-1, deg-0 redirect-to-own-row + zero,
// 2-node interleave) with QUAD/OCTO-EDGE uint4 row loads:
//   F=128: 16 lanes/row (c16=lane&15), edge sub-slot q=lane>>4 -> one load
//          instr covers 4 edges; one csr load covers 4 slot indices.
//   F=64:  8 lanes/row (c8=lane&7), q8=lane>>3 -> 8 edges/load, 1 csr
//          load per node per 8 slots.
// Halves (F=128) / quarters (F=64) gather VMEM instruction count and the
// associated min+address VALU vs R9; pkmax count unchanged (same bytes).
// Final reduce gains 1-2 extra shfl_xor stages per node (negligible).
// Results bit-identical. Matmul phase unchanged (MFMA 16x16x32 bf16).

template <int F, bool OUT_F32>
__global__ void __launch_bounds__(256, 2) sage_layer(
    const unsigned short* __restrict__ xg,  // bf16/key table [nn,F]
    const int* __restrict__ cnt, const int* __restrict__ csr,
    const short8* __restrict__ BfHi, const short8* __restrict__ BfLo, int loff,
    const float* __restrict__ bl, float* __restrict__ outf,
    unsigned short* __restrict__ outb, int nn) {
  constexpr int NPW = 8;
  constexpr int PAD = F + 4;  // dwords per A row (K=2F bf16 = F dwords) + pad
  constexpr int KS = F / 16;  // k-steps of 32 over K=2F
  constexpr bool KEYED = (F == 128);  // layer-1 table is key-transformed
  const int lane = threadIdx.x & 63;
  const int wid = threadIdx.x >> 6;
  const int blk = blockIdx.x * 32;
  __shared__ __align__(16) uint32 Abuf[32][PAD];

  for (int jp = 0; jp < NPW; jp += 2) {
    const int nla = wid * NPW + jp, nlb = nla + 1;
    const int na = blk + nla, nb = blk + nlb;
    const int sa = (na < nn) ? na : 0;  // safe row ids for sanitized loads
    const int sb = (nb < nn) ? nb : 0;
    int dga = 0, dgb = 0;
    if (na < nn) dga = cnt[na];
    if (nb < nn) dgb = cnt[nb];
    if (dga > 64) dga = 64;
    if (dgb > 64) dgb = 64;
    const int KM = max(dga, dgb);

    if constexpr (F == 128) {
      const int q = lane >> 4;    // edge sub-slot (0..3)
      const int c16 = lane & 15;  // 16B chunk within row
      uint32 m0a = 0u, m1a = 0u, m2a = 0u, m3a = 0u;
      uint32 m0b = 0u, m1b = 0u, m2b = 0u, m3b = 0u;
      uint32 sva = 0u, svb = 0u;
      if (na < nn) sva = *(const uint32*)(xg + ((size_t)na << 7) + 2 * lane);
      if (nb < nn) svb = *(const uint32*)(xg + ((size_t)nb << 7) + 2 * lane);
      if (KM > 0) {
        // floor stays 0u: identity for u16-max over keys [R8 errata]
        const int k0a = na << 6, kma = k0a + max(dga, 1) - 1;
        const int k0b = nb << 6, kmb = k0b + max(dgb, 1) - 1;
        for (int kk = 0; kk < KM; kk += 8) {
          int iaL = csr[min(k0a + kk + q, kma)], iaH = csr[min(k0a + kk + 4 + q, kma)];
          int ibL = csr[min(k0b + kk + q, kmb)], ibH = csr[min(k0b + kk + 4 + q, kmb)];
          if (!dga) { iaL = sa; iaH = sa; }  // wave-uniform (deg-0 safety)
          if (!dgb) { ibL = sb; ibH = sb; }
          uint4 AL = *(const uint4*)(xg + ((size_t)iaL << 7) + 8 * c16);
          uint4 AH = *(const uint4*)(xg + ((size_t)iaH << 7) + 8 * c16);
          uint4 BL = *(const uint4*)(xg + ((size_t)ibL << 7) + 8 * c16);
          uint4 BH = *(const uint4*)(xg + ((size_t)ibH << 7) + 8 * c16);
          m0a = pkmaxu(m0a, pkmaxu(AL.x, AH.x));
          m1a = pkmaxu(m1a, pkmaxu(AL.y, AH.y));
          m2a = pkmaxu(m2a, pkmaxu(AL.z, AH.z));
          m3a = pkmaxu(m3a, pkmaxu(AL.w, AH.w));
          m0b = pkmaxu(m0b, pkmaxu(BL.x, BH.x));
          m1b = pkmaxu(m1b, pkmaxu(BL.y, BH.y));
          m2b = pkmaxu(m2b, pkmaxu(BL.z, BH.z));
          m3b = pkmaxu(m3b, pkmaxu(BL.w, BH.w));
        }
        // reduce across the 4 edge sub-slots (q): xor 16, then 32
        m0a = pkmaxu(m0a, (uint32)__shfl_xor((int)m0a, 16));
        m1a = pkmaxu(m1a, (uint32)__shfl_xor((int)m1a, 16));
        m2a = pkmaxu(m2a, (uint32)__shfl_xor((int)m2a, 16));
        m3a = pkmaxu(m3a, (uint32)__shfl_xor((int)m3a, 16));
        m0b = pkmaxu(m0b, (uint32)__shfl_xor((int)m0b, 16));
        m1b = pkmaxu(m1b, (uint32)__shfl_xor((int)m1b, 16));
        m2b = pkmaxu(m2b, (uint32)__shfl_xor((int)m2b, 16));
        m3b = pkmaxu(m3b, (uint32)__shfl_xor((int)m3b, 16));
        m0a = pkmaxu(m0a, (uint32)__shfl_xor((int)m0a, 32));
        m1a = pkmaxu(m1a, (uint32)__shfl_xor((int)m1a, 32));
        m2a = pkmaxu(m2a, (uint32)__shfl_xor((int)m2a, 32));
        m3a = pkmaxu(m3a, (uint32)__shfl_xor((int)m3a, 32));
        m0b = pkmaxu(m0b, (uint32)__shfl_xor((int)m0b, 32));
        m1b = pkmaxu(m1b, (uint32)__shfl_xor((int)m1b, 32));
        m2b = pkmaxu(m2b, (uint32)__shfl_xor((int)m2b, 32));
        m3b = pkmaxu(m3b, (uint32)__shfl_xor((int)m3b, 32));
        if constexpr (KEYED) {
          m0a = unkey2(m0a); m1a = unkey2(m1a); m2a = unkey2(m2a); m3a = unkey2(m3a);
          m0b = unkey2(m0b); m1b = unkey2(m1b); m2b = unkey2(m2b); m3b = unkey2(m3b);
        }
        if (!dga) { m0a = 0u; m1a = 0u; m2a = 0u; m3a = 0u; }  // empty -> 0
        if (!dgb) { m0b = 0u; m1b = 0u; m2b = 0u; m3b = 0u; }
      }
      if (lane < 16) {  // agg (exact bf16) at k=[0,F); c16 == lane here
        uint4 mm;
        mm.x = m0a; mm.y = m1a; mm.z = m2a; mm.w = m3a;
        *(uint4*)&Abuf[nla][4 * c16] = mm;
        mm.x = m0b; mm.y = m1b; mm.z = m2b; mm.w = m3b;
        *(uint4*)&Abuf[nlb][4 * c16] = mm;
      }
      Abuf[nla][64 + lane] = KEYED ? unkey2(sva) : sva;  // self at k=[F,2F)
      Abuf[nlb][64 + lane] = KEYED ? unkey2(svb) : svb;
    } else {
      const int q8 = lane >> 3;  // edge sub-slot (0..7)
      const int c8 = lane & 7;   // 16B chunk within row
      uint32 m0a = 0u, m1a = 0u, m2a = 0u, m3a = 0u;
      uint32 m0b = 0u, m1b = 0u, m2b = 0u, m3b = 0u;
      uint32 sva = 0u, svb = 0u;
      if (lane < 32) {
        if (na < nn) sva = *(const uint32*)(xg + ((size_t)na << 6) + 2 * lane);
        if (nb < nn) svb = *(const uint32*)(xg + ((size_t)nb << 6) + 2 * lane);
      }
      if (KM > 0) {
        const int k0a = na << 6, kma = k0a + max(dga, 1) - 1;
        const int k0b = nb << 6, kmb = k0b + max(dgb, 1) - 1;
        for (int kk = 0; kk < KM; kk += 8) {
          int ia = csr[min(k0a + kk + q8, kma)];
          int ib = csr[min(k0b + kk + q8, kmb)];
          if (!dga) ia = sa;
          if (!dgb) ib = sb;
          uint4 A = *(const uint4*)(xg + ((size_t)ia << 6) + 8 * c8);
          uint4 B = *(const uint4*)(xg + ((size_t)ib << 6) + 8 * c8);
          m0a = pkmaxu(m0a, A.x);
          m1a = pkmaxu(m1a, A.y);
          m2a = pkmaxu(m2a, A.z);
          m3a = pkmaxu(m3a, A.w);
          m0b = pkmaxu(m0b, B.x);
          m1b = pkmaxu(m1b, B.y);
          m2b = pkmaxu(m2b, B.z);
          m3b = pkmaxu(m3b, B.w);
        }
        // reduce across the 8 edge sub-slots (q8): xor 8, 16, 32
#pragma unroll
        for (int off = 8; off <= 32; off <<= 1) {
          m0a = pkmaxu(m0a, (uint32)__shfl_xor((int)m0a, off));
          m1a = pkmaxu(m1a, (uint32)__shfl_xor((int)m1a, off));
          m2a = pkmaxu(m2a, (uint32)__shfl_xor((int)m2a, off));
          m3a = pkmaxu(m3a, (uint32)__shfl_xor((int)m3a, off));
          m0b = pkmaxu(m0b, (uint32)__shfl_xor((int)m0b, off));
          m1b = pkmaxu(m1b, (uint32)__shfl_xor((int)m1b, off));
          m2b = pkmaxu(m2b, (uint32)__shfl_xor((int)m2b, off));
          m3b = pkmaxu(m3b, (uint32)__shfl_xor((int)m3b, off));
        }
        if (!dga) { m0a = 0u; m1a = 0u; m2a = 0u; m3a = 0u; }
        if (!dgb) { m0b = 0u; m1b = 0u; m2b = 0u; m3b = 0u; }
      }
      if (lane < 8) {  // agg at k=[0,F); c8 == lane here
        uint4 mm;
        mm.x = m0a; mm.y = m1a; mm.z = m2a; mm.w = m3a;
        *(uint4*)&Abuf[nla][4 * c8] = mm;
        mm.x = m0b; mm.y = m1b; mm.z = m2b; mm.w = m3b;
        *(uint4*)&Abuf[nlb][4 * c8] = mm;
      }
      if (lane < 32) {
        Abuf[nla][32 + lane] = sva;  // self at k=[F,2F)
        Abuf[nlb][32 + lane] = svb;
      }
    }
  }
  __syncthreads();  // A matrix is block-shared by the MFMA phase

  // ---- MFMA matmul: C[32][64] = A[32][2F] * Wstack[2F][64] + b ----
  const int l15 = lane & 15, lk = lane >> 4;
  const int mt = wid & 1;           // m-tile (rows mt*16..mt*16+15)
  const int ntb = (wid >> 1) << 1;  // this wave's 2 n-tiles: ntb, ntb+1
  const int arow = mt * 16 + l15;
  float bb0 = bl[ntb * 16 + l15], bb1 = bl[ntb * 16 + 16 + l15];
  f32x4 acc0 = {bb0, bb0, bb0, bb0};
  f32x4 acc1 = {bb1, bb1, bb1, bb1};
  const int gb0 = (loff + (ntb + 0) * KS) * 64 + lane;
  const int gb1 = (loff + (ntb + 1) * KS) * 64 + lane;
#pragma unroll 2
  for (int ks = 0; ks < KS; ++ks) {
    short8 a = *(const short8*)&Abuf[arow][ks * 16 + lk * 4];
    short8 bh0 = BfHi[gb0 + ks * 64];
    short8 bl0 = BfLo[gb0 + ks * 64];
    short8 bh1 = BfHi[gb1 + ks * 64];
    short8 bl1 = BfLo[gb1 + ks * 64];
    acc0 = mfma16(a, bh0, acc0);
    acc0 = mfma16(a, bl0, acc0);
    acc1 = mfma16(a, bh1, acc1);
    acc1 = mfma16(a, bl1, acc1);
  }
  // C layout: col = lane&15, row = (lane>>4)*4 + j
#pragma unroll
  for (int j = 0; j < 4; ++j) {
    int node = blk + mt * 16 + lk * 4 + j;
    if (node < nn) {
      float r0 = fmaxf(acc0[j], 0.f);
      float r1 = fmaxf(acc1[j], 0.f);
      if constexpr (OUT_F32) {
        outf[(size_t)node * 64 + ntb * 16 + l15] = r0;
        outf[(size_t)node * 64 + ntb * 16 + 16 + l15] = r1;
      } else {
        outb[(size_t)node * 64 + ntb * 16 + l15] = f2bf(r0);
        outb[(size_t)node * 64 + ntb * 16 + 16 + l15] = f2bf(r1);
      }
    }
  }
}

// ---------------- pooling tail ----------------

__global__ void cscore_kernel(const float* __restrict__ clo, const float* __restrict__ Wc,
                              const float* __restrict__ bc, const int* __restrict__ bat,
                              float* __restrict__ cbuf, unsigned* __restrict__ cmaxU,
                              int* __restrict__ gcnt, int n) {
  int i = blockIdx.x * blockDim.x + threadIdx.x;
  int lane = threadIdx.x & 63;
  float cv = -INFINITY;
  int g = -1;
  if (i < n) {
    const float4* row = (const float4*)(clo + (size_t)i * 16);
    float4 r0 = row[0], r1 = row[1], r2 = row[2], r3 = row[3];
    cv = bc[0];
    cv += r0.x * Wc[0] + r0.y * Wc[1] + r0.z * Wc[2] + r0.w * Wc[3];
    cv += r1.x * Wc[4] + r1.y * Wc[5] + r1.z * Wc[6] + r1.w * Wc[7];
    cv += r2.x * Wc[8] + r2.y * Wc[9] + r2.z * Wc[10] + r2.w * Wc[11];
    cv += r3.x * Wc[12] + r3.y * Wc[13] + r3.z * Wc[14] + r3.w * Wc[15];
    cbuf[i] = cv;
    g = bat[i];
  }
  int g0 = __shfl(g, 0), g63 = __shfl(g, 63);
  if (g0 >= 0 && g0 == g63) {  // whole wave in one graph (batch sorted)
    float m = cv;
#pragma unroll
    for (int off = 32; off; off >>= 1) m = fmaxf(m, __shfl_down(m, off));
    if (lane == 0) {
      atomicMax(&cmaxU[g0], fkey(m));
      atomicAdd(&gcnt[g0], 64);
    }
  } else if (g >= 0) {
    atomicMax(&cmaxU[g], fkey(cv));
    atomicAdd(&gcnt[g], 1);
  }
}

__global__ void esum_kernel(const float* __restrict__ cbuf, const int* __restrict__ bat,
                            const unsigned* __restrict__ cmaxU, float* __restrict__ ebuf,
                            float* __restrict__ denom, int n) {
  int i = blockIdx.x * blockDim.x + threadIdx.x;
  int lane = threadIdx.x & 63;
  float ev = 0.f;
  int g = -1;
  if (i < n) {
    g = bat[i];
    float cm = funkey(cmaxU[g]);
    ev = expf(cbuf[i] - cm);
    ebuf[i] = ev;
  }
  int g0 = __shfl(g, 0), g63 = __shfl(g, 63);
  if (g0 >= 0 && g0 == g63) {
    float s = ev;
#pragma unroll
    for (int off = 32; off; off >>= 1) s += __shfl_down(s, off);
    if (lane == 0) atomicAdd(&denom[g0], s);
  } else if (g >= 0) {
    atomicAdd(&denom[g], ev);
  }
}

__global__ void pool_kernel(const float* __restrict__ ebuf, const float* __restrict__ denom,
                            const int* __restrict__ gcnt, const int* __restrict__ bat,
                            const float* __restrict__ h3, unsigned* __restrict__ pooledU,
                            int n) {
  const int CH = 64;
  int wave = (blockIdx.x * blockDim.x + threadIdx.x) >> 6;
  int lane = threadIdx.x & 63;
  int nb = wave * CH;
  if (nb >= n) return;
  int ne = min(nb + CH, n);
  int curg = bat[nb];
  float factor = (float)gcnt[curg] / denom[curg];
  float lmax = -INFINITY;
  for (int nd = nb; nd < ne; ++nd) {
    int g = bat[nd];
    if (g != curg) {
      atomicMax(&pooledU[(size_t)curg * 64 + lane], fkey(lmax));
      curg = g;
      factor = (float)gcnt[g] / denom[g];
      lmax = -INFINITY;
    }
    float v = ebuf[nd] * factor * h3[(size_t)nd * 64 + lane];
    lmax = fmaxf(lmax, v);
  }
  atomicMax(&pooledU[(size_t)curg * 64 + lane], fkey(lmax));
}

__global__ void final_kernel(const unsigned* __restrict__ pooledU, const float* __restrict__ Wa1,
                             const float* __restrict__ ba1, const float* __restrict__ Wa2,
                             const float* __restrict__ ba2, float* __restrict__ out, int G) {
  int g = blockIdx.x;
  int lane = threadIdx.x;  // block = 64
  float v = funkey(pooledU[(size_t)g * 64 + lane]);
  if (!isfinite(v)) v = 0.f;
  float outv = 0.f;
#pragma unroll
  for (int j = 0; j < 16; ++j) {
    float psum = v * Wa1[lane * 16 + j];
#pragma unroll
    for (int off = 32; off; off >>= 1) psum += __shfl_down(psum, off);
    if (lane == 0) outv += fmaxf(psum + ba1[j], 0.f) * Wa2[j];
  }
  if (lane == 0) out[g] = outv + ba2[0];
}

// ---------------- launch ----------------

static inline size_t alignup(size_t x) { return (x + 255) & ~(size_t)255; }

extern "C" void kernel_launch(void* const* d_in, const int* in_sizes, int n_in,
                              void* d_out, int out_size, void* d_ws, size_t ws_size,
                              hipStream_t stream) {
  const float* x = (const float*)d_in[0];
  const int* ei = (const int*)d_in[1];
  const int* bat = (const int*)d_in[2];
  const float* clo = (const float*)d_in[3];
  const float* W1l = (const float*)d_in[4];
  const float* b1l = (const float*)d_in[5];
  const float* W1r = (const float*)d_in[6];
  const float* W2l = (const float*)d_in[7];
  const float* b2l = (const float*)d_in[8];
  const float* W2r = (const float*)d_in[9];
  const float* W3l = (const float*)d_in[10];
  const float* b3l = (const float*)d_in[11];
  const float* W3r = (const float*)d_in[12];
  const float* Wc = (const float*)d_in[13];
  const float* bc = (const float*)d_in[14];
  const float* Wa1 = (const float*)d_in[15];
  const float* ba1 = (const float*)d_in[16];
  const float* Wa2 = (const float*)d_in[17];
  const float* ba2 = (const float*)d_in[18];
  float* out = (float*)d_out;

  const int N = in_sizes[2];
  const int E = in_sizes[1] / 2;
  const int G = out_size;
  const int FIN = in_sizes[0] / N;  // 128

  char* p = (char*)d_ws;
  auto carve = [&](size_t bytes) {
    char* r = p;
    p += alignup(bytes);
    return r;
  };
  const int NB = (N + (1 << BSH) - 1) >> BSH;  // bins
  const int NC = (E + CHUNK - 1) / CHUNK;      // chunks
  int* cnt = (int*)carve((size_t)N * 4);
  int* csr = (int*)carve((size_t)N * 64 * 4);  // padded slots, 256 B per node
  unsigned short* xb = (unsigned short*)carve((size_t)N * FIN * 2);  // key table; h3 overlay
  unsigned short* hb1 = (unsigned short*)carve((size_t)N * 64 * 2);
  unsigned short* hb2 = (unsigned short*)carve((size_t)N * 64 * 2);
  float* cbuf = (float*)carve((size_t)N * 4);
  float* ebuf = (float*)carve((size_t)N * 4);
  unsigned* cmaxU = (unsigned*)carve((size_t)G * 4);
  float* denom = (float*)carve((size_t)G * 4);
  int* gcnt = (int*)carve((size_t)G * 4);
  unsigned* pooledU = (unsigned*)carve((size_t)G * 64 * 4);
  uint32* Bfrag = (uint32*)carve((size_t)32768 * 4);  // MFMA B-fragments hi+lo
  int* hist = (int*)carve((size_t)NB * NC * 4);
  int* bsum = (int*)carve((size_t)NB * 4);
  int* bbase = (int*)carve((size_t)(NB + 1) * 4);
  uint32* bbuf = (uint32*)carve((size_t)E * 4);  // exactly-compacted records
  float* h3 = (float*)xb;  // xb (N*128*2 B) dead after layer1; h3 = N*64*4 B fits exactly

  const short8* BfHi = (const short8*)Bfrag;
  const short8* BfLo = (const short8*)(Bfrag + 16384);

  const int* srcv = ei;
  const int* dstv = ei + E;

  int nb = (N + 255) / 256;
  hipLaunchKernelGGL(init_kernel, dim3((G * 64 + 255) / 256), dim3(256), 0, stream, pooledU,
                     cmaxU, denom, gcnt, G * 64, G);
  int ncvt = (N * FIN) / 4;
  hipLaunchKernelGGL(cvt_key_kernel, dim3((ncvt + 255) / 256), dim3(256), 0, stream, x, xb,
                     ncvt);
  hipLaunchKernelGGL(pack_bfrag_kernel, dim3(128), dim3(256), 0, stream, W1l, W1r, W2l, W2r,
                     W3l, W3r, Bfrag);
  hipLaunchKernelGGL(hist_kernel, dim3(NC), dim3(256), 0, stream, dstv, hist, E, NB, NC);
  hipLaunchKernelGGL(rowscan_kernel, dim3((NB + 3) / 4), dim3(256), 0, stream, hist, bsum, NB,
                     NC);
  hipLaunchKernelGGL(binscan_kernel, dim3(1), dim3(64), 0, stream, bsum, bbase, NB);
  hipLaunchKernelGGL(bfill_kernel, dim3(NC), dim3(256), 0, stream, srcv, dstv, hist, bbase,
                     bbuf, E, NB, NC);
  hipLaunchKernelGGL(place_kernel, dim3(NB), dim3(256), 0, stream, bbase, bbuf, cnt, csr, N);

  // 32 nodes per block (4 waves x NPW=8)
  int nblocks32 = (N + 31) / 32;
  hipLaunchKernelGGL((sage_layer<128, false>), dim3(nblocks32), dim3(256), 0, stream, xb, cnt,
                     csr, BfHi, BfLo, 0, b1l, (float*)nullptr, hb1, N);
  hipLaunchKernelGGL((sage_layer<64, false>), dim3(nblocks32), dim3(256), 0, stream, hb1, cnt,
                     csr, BfHi, BfLo, 32, b2l, (float*)nullptr, hb2, N);
  hipLaunchKernelGGL((sage_layer<64, true>), dim3(nblocks32), dim3(256), 0, stream, hb2, cnt,
                     csr, BfHi, BfLo, 48, b3l, h3, (unsigned short*)nullptr, N);

  hipLaunchKernelGGL(cscore_kernel, dim3(nb), dim3(256), 0, stream, clo, Wc, bc, bat, cbuf,
                     cmaxU, gcnt, N);
  hipLaunchKernelGGL(esum_kernel, dim3(nb), dim3(256), 0, stream, cbuf, bat, cmaxU, ebuf, denom,
                     N);
  int pw = (N + 63) / 64;
  int pb = (pw + 3) / 4;
  hipLaunchKernelGGL(pool_kernel, dim3(pb), dim3(256), 0, stream, ebuf, denom, gcnt, bat, h3,
                     pooledU, N);
  hipLaunchKernelGGL(final_kernel, dim3(G), dim3(64), 0, stream, pooledU, Wa1, ba1, Wa2, ba2,
                     out, G);
}